// Round 1
// 11310.538 us; speedup vs baseline: 1.0495x; 1.0495x over previous
//
#include <hip/hip_runtime.h>
#include <cstdint>
#include <cstddef>

#define T_STEPS 512
#define BATCH   64
#define HD      1024
#define BH      (BATCH * HD)   // 65536
#define NBLK    256

using half8   = __attribute__((ext_vector_type(8))) _Float16;
using half4   = __attribute__((ext_vector_type(4))) _Float16;
using floatx4 = __attribute__((ext_vector_type(4))) float;
using float4v = __attribute__((ext_vector_type(4))) float;
using u64     = unsigned long long;

__device__ __forceinline__ float sigmoidf_(float x) { return 1.0f / (1.0f + __expf(-x)); }

__device__ __forceinline__ half8 cvt_h8(float4v a, float4v b) {
    half8 r;
    r[0] = (_Float16)a[0]; r[1] = (_Float16)a[1];
    r[2] = (_Float16)a[2]; r[3] = (_Float16)a[3];
    r[4] = (_Float16)b[0]; r[5] = (_Float16)b[1];
    r[6] = (_Float16)b[2]; r[7] = (_Float16)b[3];
    return r;
}

// Coherent (L2-bypassing, sc1) 16B load as two relaxed agent-scope 8B atomic
// loads. These read the L3 (the cross-XCD coherence point) directly, so NO
// buffer_inv is ever needed to observe remote writes.
__device__ __forceinline__ half8 ld_c8(const _Float16* p) {
    union { u64 u[2]; half8 h; } r;
    r.u[0] = __hip_atomic_load((const u64*)p,       __ATOMIC_RELAXED, __HIP_MEMORY_SCOPE_AGENT);
    r.u[1] = __hip_atomic_load((const u64*)(p + 4), __ATOMIC_RELAXED, __HIP_MEMORY_SCOPE_AGENT);
    return r.h;
}

// Coherent 8B store (write-through past the non-coherent per-XCD L2): remote
// readers see it once vmcnt retires — no buffer_wbl2 needed at the barrier.
__device__ __forceinline__ void st_c8(_Float16* p, u64 v) {
    __hip_atomic_store((u64*)p, v, __ATOMIC_RELAXED, __HIP_MEMORY_SCOPE_AGENT);
}

__device__ __forceinline__ u64 pack_lo16(unsigned a, unsigned b, unsigned c, unsigned d) {
    return (u64)(a & 0xffffu) | ((u64)(b & 0xffffu) << 16)
         | ((u64)(c & 0xffffu) << 32) | ((u64)(d & 0xffffu) << 48);
}
__device__ __forceinline__ u64 pack_hi16(unsigned a, unsigned b, unsigned c, unsigned d) {
    return (u64)(a >> 16) | ((u64)(b >> 16) << 16)
         | ((u64)(c >> 16) << 32) | ((u64)(d >> 16) << 48);
}

// ---------------- workspace layout ----------------
static const size_t BAR_GRP_OFF  = 0;        // 513 slots * 8 ints
static const size_t BAR_ROOT_OFF = 20480;    // 513 ints
static const size_t CH_OFF  = 24576;                               // 256 KB
static const size_t CL_OFF  = CH_OFF + (size_t)2 * BH * 2;         // 256 KB
static const size_t WX_OFF  = 1u << 20;                            // 8 MB
static const size_t WHH_OFF = WX_OFF  + (size_t)8 * 1024 * 1024;   // 8 MB
static const size_t WHL_OFF = WHH_OFF + (size_t)8 * 1024 * 1024;   // 8 MB
static const size_t XH_OFF  = WHL_OFF + (size_t)8 * 1024 * 1024;   // @25MB
static const size_t X4_OFF  = XH_OFF;                              // tier A2: X4 f16 [32768][4096]
static const size_t TIER_A2_WS = X4_OFF + (size_t)32768 * 4096 * 2;  // ~281 MB
static const size_t TIER_A_WS  = XH_OFF + (size_t)T_STEPS * BH * 2;  // 89 MB
static const size_t TIER_B_WS  = XH_OFF;                             // 25 MB

// ---------------- prep kernels ----------------
__global__ void prep_zero(int* bar) {
    int i = blockIdx.x * 256 + threadIdx.x;
    if (i < 6144) bar[i] = 0;
}

__global__ void prep_w(const float* __restrict__ Wx, const float* __restrict__ Wh,
                       _Float16* __restrict__ wx16,
                       _Float16* __restrict__ whh, _Float16* __restrict__ whl) {
    int i = blockIdx.x * 256 + threadIdx.x;
    if (i < 4 * HD * HD) {
        wx16[i] = (_Float16)Wx[i];
        float w = Wh[i];
        _Float16 h = (_Float16)w;
        whh[i] = h;
        whl[i] = (_Float16)(w - (float)h);
    }
}

__global__ void prep_x(const float* __restrict__ X, _Float16* __restrict__ xh) {
    size_t i = (size_t)blockIdx.x * 256 + threadIdx.x;
    if (i < (size_t)T_STEPS * BH) xh[i] = (_Float16)X[i];
}

// ---------------- X4 GEMM: x4[32768][4096] = X[32768][1024] @ wx16^T ----------------
__global__ __launch_bounds__(256) void x4_gemm(
    const float* __restrict__ X,
    const _Float16* __restrict__ wx16,
    _Float16* __restrict__ x4)
{
    __shared__ _Float16 sA[128][40];
    __shared__ _Float16 sB[128][40];

    const int tid  = threadIdx.x;
    const int wave = tid >> 6;
    const int lane = tid & 63;
    const int m0 = blockIdx.x * 128, n0 = blockIdx.y * 128;
    const int wm = (wave & 1) * 64,  wn = (wave >> 1) * 64;
    const int fm = lane & 15, q = lane >> 4;

    floatx4 acc[4][4];
    #pragma unroll
    for (int i = 0; i < 4; i++)
        #pragma unroll
        for (int j = 0; j < 4; j++)
            acc[i][j] = (floatx4){0.f, 0.f, 0.f, 0.f};

    for (int k0 = 0; k0 < 1024; k0 += 32) {
        {
            const int kq = (tid & 7) * 4;
            const int rb = tid >> 3;
            #pragma unroll
            for (int it = 0; it < 4; it++) {
                int row = rb + it * 32;
                float4v v = *(const float4v*)(X + (size_t)(m0 + row) * 1024 + k0 + kq);
                half4 h; h[0] = (_Float16)v[0]; h[1] = (_Float16)v[1];
                h[2] = (_Float16)v[2]; h[3] = (_Float16)v[3];
                *(half4*)&sA[row][kq] = h;
            }
        }
        {
            const int half = tid & 1;
            const int row  = tid >> 1;
            const _Float16* src = wx16 + (size_t)(n0 + row) * 1024 + k0 + half * 16;
            *(half8*)&sB[row][half * 16]     = *(const half8*)(src);
            *(half8*)&sB[row][half * 16 + 8] = *(const half8*)(src + 8);
        }
        __syncthreads();

        half8 af[4], bf[4];
        #pragma unroll
        for (int i = 0; i < 4; i++) af[i] = *(const half8*)&sA[wm + 16 * i + fm][q * 8];
        #pragma unroll
        for (int j = 0; j < 4; j++) bf[j] = *(const half8*)&sB[wn + 16 * j + fm][q * 8];
        #pragma unroll
        for (int i = 0; i < 4; i++)
            #pragma unroll
            for (int j = 0; j < 4; j++)
                acc[i][j] = __builtin_amdgcn_mfma_f32_16x16x32_f16(af[i], bf[j], acc[i][j], 0, 0, 0);
        __syncthreads();
    }

    #pragma unroll
    for (int i = 0; i < 4; i++)
        #pragma unroll
        for (int j = 0; j < 4; j++)
            #pragma unroll
            for (int r = 0; r < 4; r++) {
                int row = m0 + wm + 16 * i + q * 4 + r;
                int col = n0 + wn + 16 * j + fm;
                x4[(size_t)row * 4096 + col] = (_Float16)acc[i][j][r];
            }
}

// ---------------- grid barriers ----------------
// Legacy barrier (tier A/B kernel): acq_rel atomics -> implicit buffer_wbl2 +
// buffer_inv per leader per step. Kept for the fallback path only.
__device__ __forceinline__ void grid_bar(int* grp, int* root, int slot) {
    __syncthreads();
    if (threadIdx.x == 0) {
        int g = blockIdx.x >> 5;
        int v = __hip_atomic_fetch_add(&grp[slot * 8 + g], 1,
                                       __ATOMIC_ACQ_REL, __HIP_MEMORY_SCOPE_AGENT);
        if (v == 31)
            __hip_atomic_fetch_add(&root[slot], 1,
                                   __ATOMIC_ACQ_REL, __HIP_MEMORY_SCOPE_AGENT);
        while (__hip_atomic_load(&root[slot], __ATOMIC_RELAXED,
                                 __HIP_MEMORY_SCOPE_AGENT) < 8)
            __builtin_amdgcn_s_sleep(2);
        (void)__hip_atomic_load(&root[slot], __ATOMIC_ACQUIRE,
                                __HIP_MEMORY_SCOPE_AGENT);
    }
    __syncthreads();
}

// Relaxed barrier: NO cache maintenance. Safe because all cross-block data in
// the hot loop (c hi/lo) moves through sc1 (L2-bypass) atomic loads/stores:
//   release side: sc1 stores retire at the L3 before vmcnt drains (drained by
//     the compiler's waitcnt at __syncthreads + explicit drain below), so the
//     flag increment can only be observed after the data is globally visible.
//   acquire side: consumer loads bypass the (possibly stale) L2 and read L3;
//     they issue only after the spin's branch resolved -> no inv needed.
__device__ __forceinline__ void grid_bar_rel(int* grp, int* root, int slot) {
    __syncthreads();
    if (threadIdx.x == 0) {
        asm volatile("s_waitcnt vmcnt(0)" ::: "memory");
        int g = blockIdx.x >> 5;
        int v = __hip_atomic_fetch_add(&grp[slot * 8 + g], 1,
                                       __ATOMIC_RELAXED, __HIP_MEMORY_SCOPE_AGENT);
        if (v == 31)
            __hip_atomic_fetch_add(&root[slot], 1,
                                   __ATOMIC_RELAXED, __HIP_MEMORY_SCOPE_AGENT);
        while (__hip_atomic_load(&root[slot], __ATOMIC_RELAXED,
                                 __HIP_MEMORY_SCOPE_AGENT) < 8)
            __builtin_amdgcn_s_sleep(2);
    }
    __syncthreads();
}

// ---------------- persistent recurrence (tier A2): X4 precomputed ----------------
// 256 blocks x 1024 threads. Block owns 4 cols x 4 gates. Wave: mt=w&3 (batch
// tile), kh=w>>2 (K chunk of 256). whh in LDS, whl in registers.
// c hi/lo exchange is fully L2-bypassing (sc1) -> relaxed barrier, no wbl2/inv.
__global__ __launch_bounds__(1024, 4) void lstm_persist2(
    const _Float16* __restrict__ x4,   // [T*B][4096]
    const float* __restrict__ h0, const float* __restrict__ c0,
    const float* __restrict__ bias, const int* __restrict__ mask,
    const _Float16* __restrict__ whh, const _Float16* __restrict__ whl,
    _Float16* __restrict__ chg, _Float16* __restrict__ clg,
    int* __restrict__ barg, int* __restrict__ barr,
    float* __restrict__ out)
{
    __shared__ _Float16 s_wh[16 * 1032];    // 33 KB
    __shared__ float    s_pre[16][16][17];  // 17.4 KB
    __shared__ float    s_h[256], s_c[256];

    const int tid  = threadIdx.x;
    const int wave = tid >> 6;
    const int lane = tid & 63;
    const int j0   = blockIdx.x * 4;

    for (int idx = tid; idx < 2048; idx += 1024) {
        int n  = idx >> 7;
        int kk = (idx & 127) << 3;
        int r  = (n >> 2) * HD + j0 + (n & 3);
        *(half8*)&s_wh[n * 1032 + kk] = *(const half8*)(whh + (size_t)r * HD + kk);
    }

    float biasr[4] = {0.f, 0.f, 0.f, 0.f};
    if (tid < 256) {
        int b = tid >> 2, jj = tid & 3, j = j0 + jj;
        float cv = c0[b * HD + j];
        s_c[tid] = cv;
        s_h[tid] = h0[b * HD + j];
        #pragma unroll
        for (int g = 0; g < 4; g++) biasr[g] = bias[g * HD + j];
        // publish initial c hi/lo through the coherent (sc1) path
        _Float16 chi = (_Float16)cv;
        _Float16 clo = (_Float16)(cv - (float)chi);
        unsigned pk = (unsigned)__builtin_bit_cast(unsigned short, chi)
                    | ((unsigned)__builtin_bit_cast(unsigned short, clo) << 16);
        unsigned pk1 = __shfl_down(pk, 1);
        unsigned pk2 = __shfl_down(pk, 2);
        unsigned pk3 = __shfl_down(pk, 3);
        if (jj == 0) {
            st_c8(chg + b * HD + j0, pack_lo16(pk, pk1, pk2, pk3));
            st_c8(clg + b * HD + j0, pack_hi16(pk, pk1, pk2, pk3));
        }
    }

    const int mt    = wave & 3;
    const int kh    = wave >> 2;
    const int arow  = mt * 16 + (lane & 15);
    const int nn    = lane & 15;
    const int q     = lane >> 4;
    const int kbase = kh * 256 + q * 8;
    const int wrow  = (nn >> 2) * HD + j0 + (nn & 3);

    // whl fragments -> registers (t-invariant)
    half8 wl[8];
    #pragma unroll
    for (int k = 0; k < 8; k++)
        wl[k] = *(const half8*)(whl + (size_t)wrow * HD + kbase + k * 32);
    const _Float16* whp = &s_wh[nn * 1032 + kbase];

    grid_bar_rel(barg, barr, 0);

    for (int t = 0; t < T_STEPS; t++) {
        const int cur = t & 1;

        // prefetch this step's gate inputs + mask: overlaps the MFMA phase
        // instead of sitting on the post-__syncthreads critical path
        float xg[4] = {0.f, 0.f, 0.f, 0.f};
        int   mv    = 0;
        if (tid < 256) {
            int b = tid >> 2, jj = tid & 3, j = j0 + jj;
            #pragma unroll
            for (int g = 0; g < 4; g++)
                xg[g] = (float)x4[((size_t)t * BATCH + b) * 4096 + g * HD + j];
            mv = mask[t * BATCH + b];
        }

        const _Float16* chp = chg + (size_t)cur * BH + (size_t)arow * HD + kbase;
        const _Float16* clp = clg + (size_t)cur * BH + (size_t)arow * HD + kbase;

        floatx4 acc0 = {0.f, 0.f, 0.f, 0.f};
        floatx4 acc1 = {0.f, 0.f, 0.f, 0.f};
        #pragma unroll
        for (int k = 0; k < 8; k++) {
            half8 ah = ld_c8(chp + k * 32);
            half8 al = ld_c8(clp + k * 32);
            half8 bh = *(const half8*)(whp + k * 32);
            acc0 = __builtin_amdgcn_mfma_f32_16x16x32_f16(ah, bh, acc0, 0, 0, 0);
            acc1 = __builtin_amdgcn_mfma_f32_16x16x32_f16(al, bh, acc1, 0, 0, 0);
            acc0 = __builtin_amdgcn_mfma_f32_16x16x32_f16(ah, wl[k], acc0, 0, 0, 0);
        }
        floatx4 acc = acc0 + acc1;

        s_pre[wave][q * 4 + 0][nn] = acc[0];
        s_pre[wave][q * 4 + 1][nn] = acc[1];
        s_pre[wave][q * 4 + 2][nn] = acc[2];
        s_pre[wave][q * 4 + 3][nn] = acc[3];
        __syncthreads();

        if (tid < 256) {
            int b = tid >> 2, jj = tid & 3, j = j0 + jj;
            int m = b & 15, mtt = b >> 4;

            float pg[4];
            #pragma unroll
            for (int g = 0; g < 4; g++) {
                float s = 0.f;
                #pragma unroll
                for (int kk = 0; kk < 4; kk++)
                    s += s_pre[kk * 4 + mtt][m][g * 4 + jj];
                pg[g] = s + biasr[g] + xg[g];
            }

            float c_old = s_c[tid];
            float i_g = sigmoidf_(pg[0]);
            float f_g = sigmoidf_(pg[1]);
            float o_g = sigmoidf_(pg[2]);
            float g_g = tanhf(pg[3]);
            float c_new = f_g * c_old + i_g * g_g;
            float h_new = o_g * tanhf(c_new);

            float h_out = mv ? h_new : s_h[tid];
            float c_out = mv ? c_new : c_old;
            s_h[tid] = h_out;
            s_c[tid] = c_out;

            // pack 4 consecutive-j c values into one coherent 8B store each
            _Float16 chi = (_Float16)c_out;
            _Float16 clo = (_Float16)(c_out - (float)chi);
            unsigned pk = (unsigned)__builtin_bit_cast(unsigned short, chi)
                        | ((unsigned)__builtin_bit_cast(unsigned short, clo) << 16);
            unsigned pk1 = __shfl_down(pk, 1);
            unsigned pk2 = __shfl_down(pk, 2);
            unsigned pk3 = __shfl_down(pk, 3);

            out[(size_t)t * BH + b * HD + j] = h_out;

            if (jj == 0) {
                int nxt = cur ^ 1;
                st_c8(chg + (size_t)nxt * BH + b * HD + j0, pack_lo16(pk, pk1, pk2, pk3));
                st_c8(clg + (size_t)nxt * BH + b * HD + j0, pack_hi16(pk, pk1, pk2, pk3));
            }

            if (t == T_STEPS - 1) {
                size_t tail = (size_t)T_STEPS * BH;
                out[tail + b * HD + j]      = h_out;
                out[tail + BH + b * HD + j] = c_out;
            }
        }
        grid_bar_rel(barg, barr, t + 1);
    }
}

// ---------------- tier A/B persistent kernel (round-3, proven) ----------------
template<bool XF16>
__global__ __launch_bounds__(1024, 4) void lstm_persist(
    const float* __restrict__ X, const _Float16* __restrict__ xh,
    const float* __restrict__ h0, const float* __restrict__ c0,
    const float* __restrict__ bias, const int* __restrict__ mask,
    const _Float16* __restrict__ wx16, const _Float16* __restrict__ whh,
    const _Float16* __restrict__ whl,
    _Float16* __restrict__ chg, _Float16* __restrict__ clg,
    int* __restrict__ barg, int* __restrict__ barr,
    float* __restrict__ out)
{
    __shared__ _Float16 s_wh[16 * 1032];
    __shared__ float    s_pre[16][16][17];
    __shared__ float    s_h[256], s_c[256];

    const int tid  = threadIdx.x;
    const int wave = tid >> 6;
    const int lane = tid & 63;
    const int j0   = blockIdx.x * 4;

    for (int idx = tid; idx < 2048; idx += 1024) {
        int n  = idx >> 7;
        int kk = (idx & 127) << 3;
        int r  = (n >> 2) * HD + j0 + (n & 3);
        *(half8*)&s_wh[n * 1032 + kk] = *(const half8*)(whh + (size_t)r * HD + kk);
    }

    float biasr[4] = {0.f, 0.f, 0.f, 0.f};
    if (tid < 256) {
        int b = tid >> 2, jj = tid & 3, j = j0 + jj;
        float cv = c0[b * HD + j];
        s_c[tid] = cv;
        s_h[tid] = h0[b * HD + j];
        _Float16 hi = (_Float16)cv;
        chg[b * HD + j] = hi;
        clg[b * HD + j] = (_Float16)(cv - (float)hi);
        #pragma unroll
        for (int g = 0; g < 4; g++) biasr[g] = bias[g * HD + j];
    }
    grid_bar(barg, barr, 0);

    const int mt    = wave & 3;
    const int kh    = wave >> 2;
    const int arow  = mt * 16 + (lane & 15);
    const int nn    = lane & 15;
    const int q     = lane >> 4;
    const int kbase = kh * 256 + q * 8;
    const int wrow  = (nn >> 2) * HD + j0 + (nn & 3);

    const _Float16* wxp = wx16 + (size_t)wrow * HD + kbase;
    const _Float16* wlp = whl  + (size_t)wrow * HD + kbase;
    const _Float16* whp = (const _Float16*)&s_wh[nn * 1032 + kbase];

    for (int t = 0; t < T_STEPS; t++) {
        const int cur = t & 1;
        const _Float16* chp = chg + (size_t)cur * BH + (size_t)arow * HD + kbase;
        const _Float16* clp = clg + (size_t)cur * BH + (size_t)arow * HD + kbase;

        floatx4 acc = {0.f, 0.f, 0.f, 0.f};

        if (XF16) {
            const _Float16* xp = xh + (size_t)t * BH + (size_t)arow * HD + kbase;
            #pragma unroll 4
            for (int k = 0; k < 256; k += 32) {
                half8 av = *(const half8*)(xp + k);
                half8 bv = *(const half8*)(wxp + k);
                acc = __builtin_amdgcn_mfma_f32_16x16x32_f16(av, bv, acc, 0, 0, 0);
            }
        } else {
            const float* xp = X + (size_t)t * BH + (size_t)arow * HD + kbase;
            #pragma unroll 4
            for (int k = 0; k < 256; k += 32) {
                float4v x0 = *(const float4v*)(xp + k);
                float4v x1 = *(const float4v*)(xp + k + 4);
                half8 av = cvt_h8(x0, x1);
                half8 bv = *(const half8*)(wxp + k);
                acc = __builtin_amdgcn_mfma_f32_16x16x32_f16(av, bv, acc, 0, 0, 0);
            }
        }

        #pragma unroll 4
        for (int k = 0; k < 256; k += 32) {
            half8 ah = *(const half8*)(chp + k);
            half8 al = *(const half8*)(clp + k);
            half8 bh = *(const half8*)(whp + k);
            half8 bl = *(const half8*)(wlp + k);
            acc = __builtin_amdgcn_mfma_f32_16x16x32_f16(ah, bh, acc, 0, 0, 0);
            acc = __builtin_amdgcn_mfma_f32_16x16x32_f16(al, bh, acc, 0, 0, 0);
            acc = __builtin_amdgcn_mfma_f32_16x16x32_f16(ah, bl, acc, 0, 0, 0);
        }

        s_pre[wave][q * 4 + 0][nn] = acc[0];
        s_pre[wave][q * 4 + 1][nn] = acc[1];
        s_pre[wave][q * 4 + 2][nn] = acc[2];
        s_pre[wave][q * 4 + 3][nn] = acc[3];
        __syncthreads();

        if (tid < 256) {
            int b = tid >> 2, jj = tid & 3, j = j0 + jj;
            int m = b & 15, mtt = b >> 4;

            float pg[4];
            #pragma unroll
            for (int g = 0; g < 4; g++) {
                float s = 0.f;
                #pragma unroll
                for (int kk = 0; kk < 4; kk++)
                    s += s_pre[kk * 4 + mtt][m][g * 4 + jj];
                pg[g] = s + biasr[g];
            }

            float c_old = s_c[tid];
            float i_g = sigmoidf_(pg[0]);
            float f_g = sigmoidf_(pg[1]);
            float o_g = sigmoidf_(pg[2]);
            float g_g = tanhf(pg[3]);
            float c_new = f_g * c_old + i_g * g_g;
            float h_new = o_g * tanhf(c_new);

            int mv = mask[t * BATCH + b];
            float h_out = mv ? h_new : s_h[tid];
            float c_out = mv ? c_new : c_old;
            s_h[tid] = h_out;
            s_c[tid] = c_out;

            int nxt = cur ^ 1;
            _Float16 hi = (_Float16)c_out;
            chg[(size_t)nxt * BH + b * HD + j] = hi;
            clg[(size_t)nxt * BH + b * HD + j] = (_Float16)(c_out - (float)hi);
            out[(size_t)t * BH + b * HD + j] = h_out;

            if (t == T_STEPS - 1) {
                size_t tail = (size_t)T_STEPS * BH;
                out[tail + b * HD + j]      = h_out;
                out[tail + BH + b * HD + j] = c_out;
            }
        }
        grid_bar(barg, barr, t + 1);
    }
}

// ---------------- tiny-ws fallback: per-step kernel ----------------
__global__ void init_c_fb(const float* __restrict__ c0, float* __restrict__ cf,
                          _Float16* __restrict__ ch, _Float16* __restrict__ cl) {
    int i = blockIdx.x * 256 + threadIdx.x;
    if (i < BH) {
        float v = c0[i];
        cf[i] = v;
        _Float16 h = (_Float16)v;
        ch[i] = h;
        cl[i] = (_Float16)(v - (float)h);
    }
}

__global__ __launch_bounds__(1024) void lstm_step_fb(
    const float* __restrict__ X, const float* __restrict__ h0,
    const float* __restrict__ Wx, const float* __restrict__ Wh,
    const float* __restrict__ bias, const int* __restrict__ mask,
    float* __restrict__ cf, _Float16* __restrict__ chbuf, _Float16* __restrict__ clbuf,
    float* __restrict__ out, int t)
{
    __shared__ float lds_pre[4][64][16];
    const int tid = threadIdx.x, wave = tid >> 6, lane = tid & 63;
    const int g = wave & 3, mt = wave >> 2, j0 = blockIdx.x * 16;
    const int cur = t & 1;
    const float* cf_prev = cf + (size_t)cur * BH;
    const _Float16* ch_prev = chbuf + (size_t)cur * BH;
    const _Float16* cl_prev = clbuf + (size_t)cur * BH;
    float* cf_next = cf + (size_t)(cur ^ 1) * BH;
    _Float16* ch_next = chbuf + (size_t)(cur ^ 1) * BH;
    _Float16* cl_next = clbuf + (size_t)(cur ^ 1) * BH;
    const int arow = mt * 16 + (lane & 15);
    const int brow = g * HD + j0 + (lane & 15);
    const int koff = (lane >> 4) * 8;
    floatx4 acc = {0.f, 0.f, 0.f, 0.f};
    {
        const float* xp = X + (size_t)t * BH + (size_t)arow * HD + koff;
        const float* wp = Wx + (size_t)brow * HD + koff;
        #pragma unroll 4
        for (int k = 0; k < HD; k += 32) {
            float4v x0 = *(const float4v*)(xp + k);
            float4v x1 = *(const float4v*)(xp + k + 4);
            float4v w0 = *(const float4v*)(wp + k);
            float4v w1 = *(const float4v*)(wp + k + 4);
            acc = __builtin_amdgcn_mfma_f32_16x16x32_f16(cvt_h8(x0, x1), cvt_h8(w0, w1), acc, 0, 0, 0);
        }
    }
    {
        const _Float16* chp = ch_prev + (size_t)arow * HD + koff;
        const _Float16* clp = cl_prev + (size_t)arow * HD + koff;
        const float* whp = Wh + (size_t)brow * HD + koff;
        #pragma unroll 4
        for (int k = 0; k < HD; k += 32) {
            half8 ah = *(const half8*)(chp + k);
            half8 al = *(const half8*)(clp + k);
            float4v w0 = *(const float4v*)(whp + k);
            float4v w1 = *(const float4v*)(whp + k + 4);
            half8 bh = cvt_h8(w0, w1);
            float4v r0, r1;
            r0[0] = w0[0] - (float)bh[0]; r0[1] = w0[1] - (float)bh[1];
            r0[2] = w0[2] - (float)bh[2]; r0[3] = w0[3] - (float)bh[3];
            r1[0] = w1[0] - (float)bh[4]; r1[1] = w1[1] - (float)bh[5];
            r1[2] = w1[2] - (float)bh[6]; r1[3] = w1[3] - (float)bh[7];
            half8 bl = cvt_h8(r0, r1);
            acc = __builtin_amdgcn_mfma_f32_16x16x32_f16(ah, bh, acc, 0, 0, 0);
            acc = __builtin_amdgcn_mfma_f32_16x16x32_f16(al, bh, acc, 0, 0, 0);
            acc = __builtin_amdgcn_mfma_f32_16x16x32_f16(ah, bl, acc, 0, 0, 0);
        }
    }
    {
        const int qq = lane >> 4, col = lane & 15;
        lds_pre[g][mt * 16 + qq * 4 + 0][col] = acc[0];
        lds_pre[g][mt * 16 + qq * 4 + 1][col] = acc[1];
        lds_pre[g][mt * 16 + qq * 4 + 2][col] = acc[2];
        lds_pre[g][mt * 16 + qq * 4 + 3][col] = acc[3];
    }
    __syncthreads();
    {
        const int bl2 = tid >> 4, n = tid & 15, j = j0 + n;
        float pg[4];
        #pragma unroll
        for (int gg = 0; gg < 4; gg++) pg[gg] = lds_pre[gg][bl2][n] + bias[gg * HD + j];
        float c_old = cf_prev[bl2 * HD + j];
        float i_g = sigmoidf_(pg[0]), f_g = sigmoidf_(pg[1]);
        float o_g = sigmoidf_(pg[2]), g_g = tanhf(pg[3]);
        float c_new = f_g * c_old + i_g * g_g;
        float h_new = o_g * tanhf(c_new);
        int mv = mask[t * BATCH + bl2];
        float h_prev = (t == 0) ? h0[bl2 * HD + j] : out[(size_t)(t - 1) * BH + bl2 * HD + j];
        float h_out = mv ? h_new : h_prev;
        float c_out = mv ? c_new : c_old;
        cf_next[bl2 * HD + j] = c_out;
        _Float16 hh = (_Float16)c_out;
        ch_next[bl2 * HD + j] = hh;
        cl_next[bl2 * HD + j] = (_Float16)(c_out - (float)hh);
        out[(size_t)t * BH + bl2 * HD + j] = h_out;
        if (t == T_STEPS - 1) {
            size_t tail = (size_t)T_STEPS * BH;
            out[tail + bl2 * HD + j] = h_out;
            out[tail + BH + bl2 * HD + j] = c_out;
        }
    }
}

// ---------------- launch ----------------
extern "C" void kernel_launch(void* const* d_in, const int* in_sizes, int n_in,
                              void* d_out, int out_size, void* d_ws, size_t ws_size,
                              hipStream_t stream) {
    const float* X    = (const float*)d_in[0];
    const float* h0   = (const float*)d_in[1];
    const float* c0   = (const float*)d_in[2];
    const int*   mask = (const int*)  d_in[3];
    const float* Wx   = (const float*)d_in[4];
    const float* Wh   = (const float*)d_in[5];
    const float* bias = (const float*)d_in[6];
    float* out = (float*)d_out;
    char* ws = (char*)d_ws;

    if (ws_size >= TIER_B_WS) {
        int*      barg = (int*)(ws + BAR_GRP_OFF);
        int*      barr = (int*)(ws + BAR_ROOT_OFF);
        _Float16* chg  = (_Float16*)(ws + CH_OFF);
        _Float16* clg  = (_Float16*)(ws + CL_OFF);
        _Float16* wx16 = (_Float16*)(ws + WX_OFF);
        _Float16* whh  = (_Float16*)(ws + WHH_OFF);
        _Float16* whl  = (_Float16*)(ws + WHL_OFF);

        prep_zero<<<dim3(24), dim3(256), 0, stream>>>(barg);
        prep_w<<<dim3(16384), dim3(256), 0, stream>>>(Wx, Wh, wx16, whh, whl);

        if (ws_size >= TIER_A2_WS) {
            _Float16* x4 = (_Float16*)(ws + X4_OFF);
            x4_gemm<<<dim3(256, 32), dim3(256), 0, stream>>>(X, wx16, x4);
            void* args[] = {
                (void*)&x4, (void*)&h0, (void*)&c0, (void*)&bias, (void*)&mask,
                (void*)&whh, (void*)&whl, (void*)&chg, (void*)&clg,
                (void*)&barg, (void*)&barr, (void*)&out
            };
            hipLaunchCooperativeKernel((const void*)&lstm_persist2,
                                       dim3(NBLK), dim3(1024), args, 0, stream);
        } else {
            _Float16* xh = (_Float16*)(ws + XH_OFF);
            const bool tierA = ws_size >= TIER_A_WS;
            if (tierA)
                prep_x<<<dim3(131072), dim3(256), 0, stream>>>(X, xh);
            void* args[] = {
                (void*)&X, (void*)&xh, (void*)&h0, (void*)&c0, (void*)&bias,
                (void*)&mask, (void*)&wx16, (void*)&whh, (void*)&whl,
                (void*)&chg, (void*)&clg, (void*)&barg, (void*)&barr, (void*)&out
            };
            if (tierA)
                hipLaunchCooperativeKernel((const void*)&lstm_persist<true>,
                                           dim3(NBLK), dim3(1024), args, 0, stream);
            else
                hipLaunchCooperativeKernel((const void*)&lstm_persist<false>,
                                           dim3(NBLK), dim3(1024), args, 0, stream);
        }
    } else {
        float*    cf = (float*)ws;
        _Float16* ch = (_Float16*)(ws + 524288);
        _Float16* cl = (_Float16*)(ws + 786432);
        init_c_fb<<<dim3((BH + 255) / 256), dim3(256), 0, stream>>>(c0, cf, ch, cl);
        for (int t = 0; t < T_STEPS; t++)
            lstm_step_fb<<<dim3(64), dim3(1024), 0, stream>>>(
                X, h0, Wx, Wh, bias, mask, cf, ch, cl, out, t);
    }
}

// Round 3
// 3909.364 us; speedup vs baseline: 3.0363x; 2.8932x over previous
//
#include <hip/hip_runtime.h>
#include <cstdint>
#include <cstddef>

#define T_STEPS 512
#define BATCH   64
#define HD      1024
#define BH      (BATCH * HD)   // 65536
#define NBLK    256
#define NSG     4              // independent sub-grids (batch groups)
#define BSG     16             // batches per sub-grid
#define JBLK    16             // j columns per block (tier A2 kernel)

using half8   = __attribute__((ext_vector_type(8))) _Float16;
using half4   = __attribute__((ext_vector_type(4))) _Float16;
using floatx4 = __attribute__((ext_vector_type(4))) float;
using float4v = __attribute__((ext_vector_type(4))) float;
using u64     = unsigned long long;

__device__ __forceinline__ float sigmoidf_(float x) { return 1.0f / (1.0f + __expf(-x)); }

__device__ __forceinline__ half8 cvt_h8(float4v a, float4v b) {
    half8 r;
    r[0] = (_Float16)a[0]; r[1] = (_Float16)a[1];
    r[2] = (_Float16)a[2]; r[3] = (_Float16)a[3];
    r[4] = (_Float16)b[0]; r[5] = (_Float16)b[1];
    r[6] = (_Float16)b[2]; r[7] = (_Float16)b[3];
    return r;
}

// Plain (non-atomic) L1+L2-bypassing 8B store: data is visible at L3 (the
// cross-XCD coherence point) once vmcnt retires. Safe because the grid
// barrier fully separates the write phase from the read phase.
__device__ __forceinline__ void st_sc1_b64(_Float16* p, u64 v) {
    asm volatile("global_store_dwordx2 %0, %1, off sc0 sc1"
                 :: "v"(p), "v"(v) : "memory");
}

__device__ __forceinline__ u64 pack_lo16(unsigned a, unsigned b, unsigned c, unsigned d) {
    return (u64)(a & 0xffffu) | ((u64)(b & 0xffffu) << 16)
         | ((u64)(c & 0xffffu) << 32) | ((u64)(d & 0xffffu) << 48);
}
__device__ __forceinline__ u64 pack_hi16(unsigned a, unsigned b, unsigned c, unsigned d) {
    return (u64)(a >> 16) | ((u64)(b >> 16) << 16)
         | ((u64)(c >> 16) << 32) | ((u64)(d >> 16) << 48);
}

// ---------------- workspace layout ----------------
static const size_t BAR_GRP_OFF  = 0;        // legacy slot barrier + new padded tree
static const size_t BAR_ROOT_OFF = 20480;    // legacy root (tier A/B kernel)
static const size_t CH_OFF  = 24576;                               // 256 KB
static const size_t CL_OFF  = CH_OFF + (size_t)2 * BH * 2;         // 256 KB
static const size_t WX_OFF  = 1u << 20;                            // 8 MB
static const size_t WHH_OFF = WX_OFF  + (size_t)8 * 1024 * 1024;   // 8 MB
static const size_t WHL_OFF = WHH_OFF + (size_t)8 * 1024 * 1024;   // 8 MB
static const size_t XH_OFF  = WHL_OFF + (size_t)8 * 1024 * 1024;   // @25MB
static const size_t X4_OFF  = XH_OFF;                              // tier A2: X4 f16 [32768][4096]
static const size_t TIER_A2_WS = X4_OFF + (size_t)32768 * 4096 * 2;  // ~281 MB
static const size_t TIER_A_WS  = XH_OFF + (size_t)T_STEPS * BH * 2;  // 89 MB
static const size_t TIER_B_WS  = XH_OFF;                             // 25 MB

// ---------------- prep kernels ----------------
__global__ void prep_zero(int* bar) {
    int i = blockIdx.x * 256 + threadIdx.x;
    if (i < 6144) bar[i] = 0;
}

__global__ void prep_w(const float* __restrict__ Wx, const float* __restrict__ Wh,
                       _Float16* __restrict__ wx16,
                       _Float16* __restrict__ whh, _Float16* __restrict__ whl) {
    int i = blockIdx.x * 256 + threadIdx.x;
    if (i < 4 * HD * HD) {
        wx16[i] = (_Float16)Wx[i];
        float w = Wh[i];
        _Float16 h = (_Float16)w;
        whh[i] = h;
        whl[i] = (_Float16)(w - (float)h);
    }
}

__global__ void prep_x(const float* __restrict__ X, _Float16* __restrict__ xh) {
    size_t i = (size_t)blockIdx.x * 256 + threadIdx.x;
    if (i < (size_t)T_STEPS * BH) xh[i] = (_Float16)X[i];
}

// ---------------- X4 GEMM: x4[32768][4096] = X[32768][1024] @ wx16^T ----------------
__global__ __launch_bounds__(256) void x4_gemm(
    const float* __restrict__ X,
    const _Float16* __restrict__ wx16,
    _Float16* __restrict__ x4)
{
    __shared__ _Float16 sA[128][40];
    __shared__ _Float16 sB[128][40];

    const int tid  = threadIdx.x;
    const int wave = tid >> 6;
    const int lane = tid & 63;
    const int m0 = blockIdx.x * 128, n0 = blockIdx.y * 128;
    const int wm = (wave & 1) * 64,  wn = (wave >> 1) * 64;
    const int fm = lane & 15, q = lane >> 4;

    floatx4 acc[4][4];
    #pragma unroll
    for (int i = 0; i < 4; i++)
        #pragma unroll
        for (int j = 0; j < 4; j++)
            acc[i][j] = (floatx4){0.f, 0.f, 0.f, 0.f};

    for (int k0 = 0; k0 < 1024; k0 += 32) {
        {
            const int kq = (tid & 7) * 4;
            const int rb = tid >> 3;
            #pragma unroll
            for (int it = 0; it < 4; it++) {
                int row = rb + it * 32;
                float4v v = *(const float4v*)(X + (size_t)(m0 + row) * 1024 + k0 + kq);
                half4 h; h[0] = (_Float16)v[0]; h[1] = (_Float16)v[1];
                h[2] = (_Float16)v[2]; h[3] = (_Float16)v[3];
                *(half4*)&sA[row][kq] = h;
            }
        }
        {
            const int half = tid & 1;
            const int row  = tid >> 1;
            const _Float16* src = wx16 + (size_t)(n0 + row) * 1024 + k0 + half * 16;
            *(half8*)&sB[row][half * 16]     = *(const half8*)(src);
            *(half8*)&sB[row][half * 16 + 8] = *(const half8*)(src + 8);
        }
        __syncthreads();

        half8 af[4], bf[4];
        #pragma unroll
        for (int i = 0; i < 4; i++) af[i] = *(const half8*)&sA[wm + 16 * i + fm][q * 8];
        #pragma unroll
        for (int j = 0; j < 4; j++) bf[j] = *(const half8*)&sB[wn + 16 * j + fm][q * 8];
        #pragma unroll
        for (int i = 0; i < 4; i++)
            #pragma unroll
            for (int j = 0; j < 4; j++)
                acc[i][j] = __builtin_amdgcn_mfma_f32_16x16x32_f16(af[i], bf[j], acc[i][j], 0, 0, 0);
        __syncthreads();
    }

    #pragma unroll
    for (int i = 0; i < 4; i++)
        #pragma unroll
        for (int j = 0; j < 4; j++)
            #pragma unroll
            for (int r = 0; r < 4; r++) {
                int row = m0 + wm + 16 * i + q * 4 + r;
                int col = n0 + wn + 16 * j + fm;
                x4[(size_t)row * 4096 + col] = (_Float16)acc[i][j][r];
            }
}

// ---------------- legacy grid barrier (tier A/B kernel) ----------------
__device__ __forceinline__ void grid_bar(int* grp, int* root, int slot) {
    __syncthreads();
    if (threadIdx.x == 0) {
        int g = blockIdx.x >> 5;
        int v = __hip_atomic_fetch_add(&grp[slot * 8 + g], 1,
                                       __ATOMIC_ACQ_REL, __HIP_MEMORY_SCOPE_AGENT);
        if (v == 31)
            __hip_atomic_fetch_add(&root[slot], 1,
                                   __ATOMIC_ACQ_REL, __HIP_MEMORY_SCOPE_AGENT);
        while (__hip_atomic_load(&root[slot], __ATOMIC_RELAXED,
                                 __HIP_MEMORY_SCOPE_AGENT) < 8)
            __builtin_amdgcn_s_sleep(2);
        (void)__hip_atomic_load(&root[slot], __ATOMIC_ACQUIRE,
                                __HIP_MEMORY_SCOPE_AGENT);
    }
    __syncthreads();
}

// ---------------- sub-grid monotone barrier (tier A2) ----------------
// Two-level tree per 64-block sub-grid; EVERY counter on its own 256B line
// (max 8 serialized RMWs per line). Monotone counters: no slot arrays, no
// re-zeroing. Release correctness: EVERY thread drains vmcnt before the
// s_barrier, so all waves' sc0|sc1 payload stores are L3-visible before the
// leader's flag add. Acquire correctness: consumer loads are sc0|sc1 (bypass
// L1/L2, read L3) and issue only after the spin's branch resolves.
__device__ __forceinline__ void gbar(int* grp, int* root, int& bcnt) {
    asm volatile("s_waitcnt vmcnt(0)" ::: "memory");
    __syncthreads();
    bcnt++;
    if (threadIdx.x == 0) {
        int v = __hip_atomic_fetch_add(grp, 1, __ATOMIC_RELAXED, __HIP_MEMORY_SCOPE_AGENT);
        if (v == 8 * bcnt - 1)
            __hip_atomic_fetch_add(root, 1, __ATOMIC_RELAXED, __HIP_MEMORY_SCOPE_AGENT);
        while (__hip_atomic_load(root, __ATOMIC_RELAXED, __HIP_MEMORY_SCOPE_AGENT) < 8 * bcnt)
            __builtin_amdgcn_s_sleep(2);
    }
    __syncthreads();
}

// ---------------- persistent recurrence (tier A2, batch-sliced) ----------------
// 4 independent sub-grids x 64 blocks x 512 threads. Sub-grid owns 16 batches;
// block owns 16 j-cols x 4 gates; ALL weights (hi+lo) in registers (128 VGPRs);
// wave = K-chunk of 128 (8 waves); c hi/lo exchanged via sc0|sc1 dwordx4.
// min-waves=1: ~210 VGPR peak needs the 256-VGPR budget — (512,2) would spill
// to scratch (suspected round-2 container kill).
__global__ __launch_bounds__(512, 1) void lstm_persist3(
    const _Float16* __restrict__ x4,   // [T*B][4096]
    const float* __restrict__ h0, const float* __restrict__ c0,
    const float* __restrict__ bias, const int* __restrict__ mask,
    const _Float16* __restrict__ whh, const _Float16* __restrict__ whl,
    _Float16* __restrict__ chg, _Float16* __restrict__ clg,
    int* __restrict__ bar,
    float* __restrict__ out)
{
    __shared__ float s_pre[8][4][16][18];   // 36.9 KB
    __shared__ float s_h[256], s_c[256];

    const int tid  = threadIdx.x;
    const int wave = tid >> 6;     // 0..7 = K-chunk
    const int lane = tid & 63;
    const int sg   = blockIdx.x >> 6;   // 0..3
    const int lb   = blockIdx.x & 63;   // 0..63
    const int b0   = sg * BSG;
    const int j0   = lb * JBLK;

    int* grp  = bar + (sg * 9 + (lb >> 3)) * 64;   // 256B-padded counters
    int* root = bar + (sg * 9 + 8) * 64;
    int  bcnt = 0;

    const int nn    = lane & 15;          // j-local (B-frag row)
    const int q     = lane >> 4;
    const int kbase = wave * 128 + q * 8;
    const int arow  = lane & 15;          // batch-local (A-frag row)

    // ---- all weights (hi + lo) into registers: 4 gates x 4 k-iters ----
    half8 wh_[4][4], wl_[4][4];
    #pragma unroll
    for (int g = 0; g < 4; g++) {
        const size_t wr = (size_t)(g * HD + j0 + nn) * HD + kbase;
        #pragma unroll
        for (int k = 0; k < 4; k++) {
            wh_[g][k] = *(const half8*)(whh + wr + k * 32);
            wl_[g][k] = *(const half8*)(whl + wr + k * 32);
        }
    }

    // ---- init gate state, publish c0 ----
    float biasr[4] = {0.f, 0.f, 0.f, 0.f};
    if (tid < 256) {
        int bl = tid >> 4, n = tid & 15;
        int b = b0 + bl, j = j0 + n;
        float cv = c0[b * HD + j];
        s_c[tid] = cv;
        s_h[tid] = h0[b * HD + j];
        #pragma unroll
        for (int g = 0; g < 4; g++) biasr[g] = bias[g * HD + j];

        _Float16 chi = (_Float16)cv;
        _Float16 clo = (_Float16)(cv - (float)chi);
        unsigned pk = (unsigned)__builtin_bit_cast(unsigned short, chi)
                    | ((unsigned)__builtin_bit_cast(unsigned short, clo) << 16);
        unsigned p1 = __shfl_down(pk, 1);
        unsigned p2 = __shfl_down(pk, 2);
        unsigned p3 = __shfl_down(pk, 3);
        if ((n & 3) == 0) {
            st_sc1_b64(chg + b * HD + j0 + (n & ~3), pack_lo16(pk, p1, p2, p3));
            st_sc1_b64(clg + b * HD + j0 + (n & ~3), pack_hi16(pk, p1, p2, p3));
        }
    }
    gbar(grp, root, bcnt);

    for (int t = 0; t < T_STEPS; t++) {
        const int cur = t & 1;

        // issue this step's gate-input + mask loads FIRST: their HBM latency
        // hides under the c-load (L3) + MFMA phase below
        float xg[4] = {0.f, 0.f, 0.f, 0.f};
        int   mv    = 0;
        if (tid < 256) {
            int b = b0 + (tid >> 4), j = j0 + (tid & 15);
            #pragma unroll
            for (int g = 0; g < 4; g++)
                xg[g] = (float)x4[((size_t)t * BATCH + b) * 4096 + g * HD + j];
            mv = mask[t * BATCH + b];
        }

        const _Float16* chp = chg + (size_t)cur * BH + (size_t)(b0 + arow) * HD + kbase;
        const _Float16* clp = clg + (size_t)cur * BH + (size_t)(b0 + arow) * HD + kbase;

        // 8x b128 sc0|sc1 loads (bypass L1+L2, read L3) + single wait,
        // all inside one asm so nothing consumes the regs before the wait.
        half8 a0, a1, a2, a3, l0, l1, l2, l3;
        asm volatile(
            "global_load_dwordx4 %0, %8, off sc0 sc1\n\t"
            "global_load_dwordx4 %1, %8, off offset:64 sc0 sc1\n\t"
            "global_load_dwordx4 %2, %8, off offset:128 sc0 sc1\n\t"
            "global_load_dwordx4 %3, %8, off offset:192 sc0 sc1\n\t"
            "global_load_dwordx4 %4, %9, off sc0 sc1\n\t"
            "global_load_dwordx4 %5, %9, off offset:64 sc0 sc1\n\t"
            "global_load_dwordx4 %6, %9, off offset:128 sc0 sc1\n\t"
            "global_load_dwordx4 %7, %9, off offset:192 sc0 sc1\n\t"
            "s_waitcnt vmcnt(0)"
            : "=&v"(a0), "=&v"(a1), "=&v"(a2), "=&v"(a3),
              "=&v"(l0), "=&v"(l1), "=&v"(l2), "=&v"(l3)
            : "v"(chp), "v"(clp)
            : "memory");

        floatx4 acc[4];
        #pragma unroll
        for (int g = 0; g < 4; g++) acc[g] = (floatx4){0.f, 0.f, 0.f, 0.f};
        #pragma unroll
        for (int g = 0; g < 4; g++) {
            floatx4 t0 = acc[g];
            t0 = __builtin_amdgcn_mfma_f32_16x16x32_f16(a0, wh_[g][0], t0, 0, 0, 0);
            t0 = __builtin_amdgcn_mfma_f32_16x16x32_f16(l0, wh_[g][0], t0, 0, 0, 0);
            t0 = __builtin_amdgcn_mfma_f32_16x16x32_f16(a0, wl_[g][0], t0, 0, 0, 0);
            t0 = __builtin_amdgcn_mfma_f32_16x16x32_f16(a1, wh_[g][1], t0, 0, 0, 0);
            t0 = __builtin_amdgcn_mfma_f32_16x16x32_f16(l1, wh_[g][1], t0, 0, 0, 0);
            t0 = __builtin_amdgcn_mfma_f32_16x16x32_f16(a1, wl_[g][1], t0, 0, 0, 0);
            t0 = __builtin_amdgcn_mfma_f32_16x16x32_f16(a2, wh_[g][2], t0, 0, 0, 0);
            t0 = __builtin_amdgcn_mfma_f32_16x16x32_f16(l2, wh_[g][2], t0, 0, 0, 0);
            t0 = __builtin_amdgcn_mfma_f32_16x16x32_f16(a2, wl_[g][2], t0, 0, 0, 0);
            t0 = __builtin_amdgcn_mfma_f32_16x16x32_f16(a3, wh_[g][3], t0, 0, 0, 0);
            t0 = __builtin_amdgcn_mfma_f32_16x16x32_f16(l3, wh_[g][3], t0, 0, 0, 0);
            t0 = __builtin_amdgcn_mfma_f32_16x16x32_f16(a3, wl_[g][3], t0, 0, 0, 0);
            acc[g] = t0;
        }

        #pragma unroll
        for (int g = 0; g < 4; g++) {
            s_pre[wave][g][q * 4 + 0][nn] = acc[g][0];
            s_pre[wave][g][q * 4 + 1][nn] = acc[g][1];
            s_pre[wave][g][q * 4 + 2][nn] = acc[g][2];
            s_pre[wave][g][q * 4 + 3][nn] = acc[g][3];
        }
        __syncthreads();

        if (tid < 256) {
            int bl = tid >> 4, n = tid & 15;
            int b = b0 + bl, j = j0 + n;

            float pg[4];
            #pragma unroll
            for (int g = 0; g < 4; g++) {
                float s = xg[g] + biasr[g];
                #pragma unroll
                for (int kh = 0; kh < 8; kh++)
                    s += s_pre[kh][g][bl][n];
                pg[g] = s;
            }

            float c_old = s_c[tid];
            float i_g = sigmoidf_(pg[0]);
            float f_g = sigmoidf_(pg[1]);
            float o_g = sigmoidf_(pg[2]);
            float g_g = tanhf(pg[3]);
            float c_new = f_g * c_old + i_g * g_g;
            float h_new = o_g * tanhf(c_new);

            float h_out = mv ? h_new : s_h[tid];
            float c_out = mv ? c_new : c_old;
            s_h[tid] = h_out;
            s_c[tid] = c_out;

            // full-granule out store: 16 consecutive floats per (block,b) row
            out[(size_t)t * BH + (size_t)b * HD + j] = h_out;

            _Float16 chi = (_Float16)c_out;
            _Float16 clo = (_Float16)(c_out - (float)chi);
            unsigned pk = (unsigned)__builtin_bit_cast(unsigned short, chi)
                        | ((unsigned)__builtin_bit_cast(unsigned short, clo) << 16);
            unsigned p1 = __shfl_down(pk, 1);
            unsigned p2 = __shfl_down(pk, 2);
            unsigned p3 = __shfl_down(pk, 3);
            if ((n & 3) == 0) {
                int nxt = cur ^ 1;
                st_sc1_b64(chg + (size_t)nxt * BH + (size_t)b * HD + j0 + (n & ~3),
                           pack_lo16(pk, p1, p2, p3));
                st_sc1_b64(clg + (size_t)nxt * BH + (size_t)b * HD + j0 + (n & ~3),
                           pack_hi16(pk, p1, p2, p3));
            }

            if (t == T_STEPS - 1) {
                size_t tail = (size_t)T_STEPS * BH;
                out[tail + (size_t)b * HD + j]      = h_out;
                out[tail + BH + (size_t)b * HD + j] = c_out;
            }
        }
        gbar(grp, root, bcnt);
    }
}

// ---------------- tier A/B persistent kernel (round-3, proven) ----------------
template<bool XF16>
__global__ __launch_bounds__(1024, 4) void lstm_persist(
    const float* __restrict__ X, const _Float16* __restrict__ xh,
    const float* __restrict__ h0, const float* __restrict__ c0,
    const float* __restrict__ bias, const int* __restrict__ mask,
    const _Float16* __restrict__ wx16, const _Float16* __restrict__ whh,
    const _Float16* __restrict__ whl,
    _Float16* __restrict__ chg, _Float16* __restrict__ clg,
    int* __restrict__ barg, int* __restrict__ barr,
    float* __restrict__ out)
{
    __shared__ _Float16 s_wh[16 * 1032];
    __shared__ float    s_pre[16][16][17];
    __shared__ float    s_h[256], s_c[256];

    const int tid  = threadIdx.x;
    const int wave = tid >> 6;
    const int lane = tid & 63;
    const int j0   = blockIdx.x * 4;

    for (int idx = tid; idx < 2048; idx += 1024) {
        int n  = idx >> 7;
        int kk = (idx & 127) << 3;
        int r  = (n >> 2) * HD + j0 + (n & 3);
        *(half8*)&s_wh[n * 1032 + kk] = *(const half8*)(whh + (size_t)r * HD + kk);
    }

    float biasr[4] = {0.f, 0.f, 0.f, 0.f};
    if (tid < 256) {
        int b = tid >> 2, jj = tid & 3, j = j0 + jj;
        float cv = c0[b * HD + j];
        s_c[tid] = cv;
        s_h[tid] = h0[b * HD + j];
        _Float16 hi = (_Float16)cv;
        chg[b * HD + j] = hi;
        clg[b * HD + j] = (_Float16)(cv - (float)hi);
        #pragma unroll
        for (int g = 0; g < 4; g++) biasr[g] = bias[g * HD + j];
    }
    grid_bar(barg, barr, 0);

    const int mt    = wave & 3;
    const int kh    = wave >> 2;
    const int arow  = mt * 16 + (lane & 15);
    const int nn    = lane & 15;
    const int q     = lane >> 4;
    const int kbase = kh * 256 + q * 8;
    const int wrow  = (nn >> 2) * HD + j0 + (nn & 3);

    const _Float16* wxp = wx16 + (size_t)wrow * HD + kbase;
    const _Float16* wlp = whl  + (size_t)wrow * HD + kbase;
    const _Float16* whp = (const _Float16*)&s_wh[nn * 1032 + kbase];

    for (int t = 0; t < T_STEPS; t++) {
        const int cur = t & 1;
        const _Float16* chp = chg + (size_t)cur * BH + (size_t)arow * HD + kbase;
        const _Float16* clp = clg + (size_t)cur * BH + (size_t)arow * HD + kbase;

        floatx4 acc = {0.f, 0.f, 0.f, 0.f};

        if (XF16) {
            const _Float16* xp = xh + (size_t)t * BH + (size_t)arow * HD + kbase;
            #pragma unroll 4
            for (int k = 0; k < 256; k += 32) {
                half8 av = *(const half8*)(xp + k);
                half8 bv = *(const half8*)(wxp + k);
                acc = __builtin_amdgcn_mfma_f32_16x16x32_f16(av, bv, acc, 0, 0, 0);
            }
        } else {
            const float* xp = X + (size_t)t * BH + (size_t)arow * HD + kbase;
            #pragma unroll 4
            for (int k = 0; k < 256; k += 32) {
                float4v x0 = *(const float4v*)(xp + k);
                float4v x1 = *(const float4v*)(xp + k + 4);
                half8 av = cvt_h8(x0, x1);
                half8 bv = *(const half8*)(wxp + k);
                acc = __builtin_amdgcn_mfma_f32_16x16x32_f16(av, bv, acc, 0, 0, 0);
            }
        }

        #pragma unroll 4
        for (int k = 0; k < 256; k += 32) {
            half8 ah = *(const half8*)(chp + k);
            half8 al = *(const half8*)(clp + k);
            half8 bh = *(const half8*)(whp + k);
            half8 bl = *(const half8*)(wlp + k);
            acc = __builtin_amdgcn_mfma_f32_16x16x32_f16(ah, bh, acc, 0, 0, 0);
            acc = __builtin_amdgcn_mfma_f32_16x16x32_f16(al, bh, acc, 0, 0, 0);
            acc = __builtin_amdgcn_mfma_f32_16x16x32_f16(ah, bl, acc, 0, 0, 0);
        }

        s_pre[wave][q * 4 + 0][nn] = acc[0];
        s_pre[wave][q * 4 + 1][nn] = acc[1];
        s_pre[wave][q * 4 + 2][nn] = acc[2];
        s_pre[wave][q * 4 + 3][nn] = acc[3];
        __syncthreads();

        if (tid < 256) {
            int b = tid >> 2, jj = tid & 3, j = j0 + jj;
            int m = b & 15, mtt = b >> 4;

            float pg[4];
            #pragma unroll
            for (int g = 0; g < 4; g++) {
                float s = 0.f;
                #pragma unroll
                for (int kk = 0; kk < 4; kk++)
                    s += s_pre[kk * 4 + mtt][m][g * 4 + jj];
                pg[g] = s + biasr[g];
            }

            float c_old = s_c[tid];
            float i_g = sigmoidf_(pg[0]);
            float f_g = sigmoidf_(pg[1]);
            float o_g = sigmoidf_(pg[2]);
            float g_g = tanhf(pg[3]);
            float c_new = f_g * c_old + i_g * g_g;
            float h_new = o_g * tanhf(c_new);

            int mv = mask[t * BATCH + b];
            float h_out = mv ? h_new : s_h[tid];
            float c_out = mv ? c_new : c_old;
            s_h[tid] = h_out;
            s_c[tid] = c_out;

            int nxt = cur ^ 1;
            _Float16 hi = (_Float16)c_out;
            chg[(size_t)nxt * BH + b * HD + j] = hi;
            clg[(size_t)nxt * BH + b * HD + j] = (_Float16)(c_out - (float)hi);
            out[(size_t)t * BH + b * HD + j] = h_out;

            if (t == T_STEPS - 1) {
                size_t tail = (size_t)T_STEPS * BH;
                out[tail + b * HD + j]      = h_out;
                out[tail + BH + b * HD + j] = c_out;
            }
        }
        grid_bar(barg, barr, t + 1);
    }
}

// ---------------- tiny-ws fallback: per-step kernel ----------------
__global__ void init_c_fb(const float* __restrict__ c0, float* __restrict__ cf,
                          _Float16* __restrict__ ch, _Float16* __restrict__ cl) {
    int i = blockIdx.x * 256 + threadIdx.x;
    if (i < BH) {
        float v = c0[i];
        cf[i] = v;
        _Float16 h = (_Float16)v;
        ch[i] = h;
        cl[i] = (_Float16)(v - (float)h);
    }
}

__global__ __launch_bounds__(1024) void lstm_step_fb(
    const float* __restrict__ X, const float* __restrict__ h0,
    const float* __restrict__ Wx, const float* __restrict__ Wh,
    const float* __restrict__ bias, const int* __restrict__ mask,
    float* __restrict__ cf, _Float16* __restrict__ chbuf, _Float16* __restrict__ clbuf,
    float* __restrict__ out, int t)
{
    __shared__ float lds_pre[4][64][16];
    const int tid = threadIdx.x, wave = tid >> 6, lane = tid & 63;
    const int g = wave & 3, mt = wave >> 2, j0 = blockIdx.x * 16;
    const int cur = t & 1;
    const float* cf_prev = cf + (size_t)cur * BH;
    const _Float16* ch_prev = chbuf + (size_t)cur * BH;
    const _Float16* cl_prev = clbuf + (size_t)cur * BH;
    float* cf_next = cf + (size_t)(cur ^ 1) * BH;
    _Float16* ch_next = chbuf + (size_t)(cur ^ 1) * BH;
    _Float16* cl_next = clbuf + (size_t)(cur ^ 1) * BH;
    const int arow = mt * 16 + (lane & 15);
    const int brow = g * HD + j0 + (lane & 15);
    const int koff = (lane >> 4) * 8;
    floatx4 acc = {0.f, 0.f, 0.f, 0.f};
    {
        const float* xp = X + (size_t)t * BH + (size_t)arow * HD + koff;
        const float* wp = Wx + (size_t)brow * HD + koff;
        #pragma unroll 4
        for (int k = 0; k < HD; k += 32) {
            float4v x0 = *(const float4v*)(xp + k);
            float4v x1 = *(const float4v*)(xp + k + 4);
            float4v w0 = *(const float4v*)(wp + k);
            float4v w1 = *(const float4v*)(wp + k + 4);
            acc = __builtin_amdgcn_mfma_f32_16x16x32_f16(cvt_h8(x0, x1), cvt_h8(w0, w1), acc, 0, 0, 0);
        }
    }
    {
        const _Float16* chp = ch_prev + (size_t)arow * HD + koff;
        const _Float16* clp = cl_prev + (size_t)arow * HD + koff;
        const float* whp = Wh + (size_t)brow * HD + koff;
        #pragma unroll 4
        for (int k = 0; k < HD; k += 32) {
            half8 ah = *(const half8*)(chp + k);
            half8 al = *(const half8*)(clp + k);
            float4v w0 = *(const float4v*)(whp + k);
            float4v w1 = *(const float4v*)(whp + k + 4);
            half8 bh = cvt_h8(w0, w1);
            float4v r0, r1;
            r0[0] = w0[0] - (float)bh[0]; r0[1] = w0[1] - (float)bh[1];
            r0[2] = w0[2] - (float)bh[2]; r0[3] = w0[3] - (float)bh[3];
            r1[0] = w1[0] - (float)bh[4]; r1[1] = w1[1] - (float)bh[5];
            r1[2] = w1[2] - (float)bh[6]; r1[3] = w1[3] - (float)bh[7];
            half8 bl = cvt_h8(r0, r1);
            acc = __builtin_amdgcn_mfma_f32_16x16x32_f16(ah, bh, acc, 0, 0, 0);
            acc = __builtin_amdgcn_mfma_f32_16x16x32_f16(al, bh, acc, 0, 0, 0);
            acc = __builtin_amdgcn_mfma_f32_16x16x32_f16(ah, bl, acc, 0, 0, 0);
        }
    }
    {
        const int qq = lane >> 4, col = lane & 15;
        lds_pre[g][mt * 16 + qq * 4 + 0][col] = acc[0];
        lds_pre[g][mt * 16 + qq * 4 + 1][col] = acc[1];
        lds_pre[g][mt * 16 + qq * 4 + 2][col] = acc[2];
        lds_pre[g][mt * 16 + qq * 4 + 3][col] = acc[3];
    }
    __syncthreads();
    {
        const int bl2 = tid >> 4, n = tid & 15, j = j0 + n;
        float pg[4];
        #pragma unroll
        for (int gg = 0; gg < 4; gg++) pg[gg] = lds_pre[gg][bl2][n] + bias[gg * HD + j];
        float c_old = cf_prev[bl2 * HD + j];
        float i_g = sigmoidf_(pg[0]), f_g = sigmoidf_(pg[1]);
        float o_g = sigmoidf_(pg[2]), g_g = tanhf(pg[3]);
        float c_new = f_g * c_old + i_g * g_g;
        float h_new = o_g * tanhf(c_new);
        int mv = mask[t * BATCH + bl2];
        float h_prev = (t == 0) ? h0[bl2 * HD + j] : out[(size_t)(t - 1) * BH + bl2 * HD + j];
        float h_out = mv ? h_new : h_prev;
        float c_out = mv ? c_new : c_old;
        cf_next[bl2 * HD + j] = c_out;
        _Float16 hh = (_Float16)c_out;
        ch_next[bl2 * HD + j] = hh;
        cl_next[bl2 * HD + j] = (_Float16)(c_out - (float)hh);
        out[(size_t)t * BH + bl2 * HD + j] = h_out;
        if (t == T_STEPS - 1) {
            size_t tail = (size_t)T_STEPS * BH;
            out[tail + bl2 * HD + j] = h_out;
            out[tail + BH + bl2 * HD + j] = c_out;
        }
    }
}

// ---------------- launch ----------------
extern "C" void kernel_launch(void* const* d_in, const int* in_sizes, int n_in,
                              void* d_out, int out_size, void* d_ws, size_t ws_size,
                              hipStream_t stream) {
    const float* X    = (const float*)d_in[0];
    const float* h0   = (const float*)d_in[1];
    const float* c0   = (const float*)d_in[2];
    const int*   mask = (const int*)  d_in[3];
    const float* Wx   = (const float*)d_in[4];
    const float* Wh   = (const float*)d_in[5];
    const float* bias = (const float*)d_in[6];
    float* out = (float*)d_out;
    char* ws = (char*)d_ws;

    if (ws_size >= TIER_B_WS) {
        int*      barg = (int*)(ws + BAR_GRP_OFF);
        int*      barr = (int*)(ws + BAR_ROOT_OFF);
        _Float16* chg  = (_Float16*)(ws + CH_OFF);
        _Float16* clg  = (_Float16*)(ws + CL_OFF);
        _Float16* wx16 = (_Float16*)(ws + WX_OFF);
        _Float16* whh  = (_Float16*)(ws + WHH_OFF);
        _Float16* whl  = (_Float16*)(ws + WHL_OFF);

        prep_zero<<<dim3(24), dim3(256), 0, stream>>>(barg);
        prep_w<<<dim3(16384), dim3(256), 0, stream>>>(Wx, Wh, wx16, whh, whl);

        if (ws_size >= TIER_A2_WS) {
            _Float16* x4 = (_Float16*)(ws + X4_OFF);
            x4_gemm<<<dim3(256, 32), dim3(256), 0, stream>>>(X, wx16, x4);
            void* args[] = {
                (void*)&x4, (void*)&h0, (void*)&c0, (void*)&bias, (void*)&mask,
                (void*)&whh, (void*)&whl, (void*)&chg, (void*)&clg,
                (void*)&barg, (void*)&out
            };
            hipLaunchCooperativeKernel((const void*)&lstm_persist3,
                                       dim3(NBLK), dim3(512), args, 0, stream);
        } else {
            _Float16* xh = (_Float16*)(ws + XH_OFF);
            const bool tierA = ws_size >= TIER_A_WS;
            if (tierA)
                prep_x<<<dim3(131072), dim3(256), 0, stream>>>(X, xh);
            void* args[] = {
                (void*)&X, (void*)&xh, (void*)&h0, (void*)&c0, (void*)&bias,
                (void*)&mask, (void*)&wx16, (void*)&whh, (void*)&whl,
                (void*)&chg, (void*)&clg, (void*)&barg, (void*)&barr, (void*)&out
            };
            if (tierA)
                hipLaunchCooperativeKernel((const void*)&lstm_persist<true>,
                                           dim3(NBLK), dim3(1024), args, 0, stream);
            else
                hipLaunchCooperativeKernel((const void*)&lstm_persist<false>,
                                           dim3(NBLK), dim3(1024), args, 0, stream);
        }
    } else {
        float*    cf = (float*)ws;
        _Float16* ch = (_Float16*)(ws + 524288);
        _Float16* cl = (_Float16*)(ws + 786432);
        init_c_fb<<<dim3((BH + 255) / 256), dim3(256), 0, stream>>>(c0, cf, ch, cl);
        for (int t = 0; t < T_STEPS; t++)
            lstm_step_fb<<<dim3(64), dim3(1024), 0, stream>>>(
                X, h0, Wx, Wh, bias, mask, cf, ch, cl, out, t);
    }
}

// Round 4
// 3168.968 us; speedup vs baseline: 3.7457x; 1.2336x over previous
//
#include <hip/hip_runtime.h>
#include <cstdint>
#include <cstddef>

#define T_STEPS 512
#define BATCH   64
#define HD      1024
#define BH      (BATCH * HD)   // 65536
#define NBLK    256
#define NSG     4              // independent sub-grids (batch groups)
#define BSG     16             // batches per sub-grid
#define JBLK    16             // j columns per block (tier A2 kernel)

using half8   = __attribute__((ext_vector_type(8))) _Float16;
using half4   = __attribute__((ext_vector_type(4))) _Float16;
using floatx4 = __attribute__((ext_vector_type(4))) float;
using float4v = __attribute__((ext_vector_type(4))) float;
using u64     = unsigned long long;

__device__ __forceinline__ float sigmoidf_(float x) { return 1.0f / (1.0f + __expf(-x)); }

__device__ __forceinline__ half8 cvt_h8(float4v a, float4v b) {
    half8 r;
    r[0] = (_Float16)a[0]; r[1] = (_Float16)a[1];
    r[2] = (_Float16)a[2]; r[3] = (_Float16)a[3];
    r[4] = (_Float16)b[0]; r[5] = (_Float16)b[1];
    r[6] = (_Float16)b[2]; r[7] = (_Float16)b[3];
    return r;
}

// Plain (non-atomic) L1+L2-bypassing 8B store: data is visible at L3 (the
// cross-XCD coherence point) once vmcnt retires.
__device__ __forceinline__ void st_sc1_b64(_Float16* p, u64 v) {
    asm volatile("global_store_dwordx2 %0, %1, off sc0 sc1"
                 :: "v"(p), "v"(v) : "memory");
}

__device__ __forceinline__ u64 pack_lo16(unsigned a, unsigned b, unsigned c, unsigned d) {
    return (u64)(a & 0xffffu) | ((u64)(b & 0xffffu) << 16)
         | ((u64)(c & 0xffffu) << 32) | ((u64)(d & 0xffffu) << 48);
}
__device__ __forceinline__ u64 pack_hi16(unsigned a, unsigned b, unsigned c, unsigned d) {
    return (u64)(a >> 16) | ((u64)(b >> 16) << 16)
         | ((u64)(c >> 16) << 32) | ((u64)(d >> 16) << 48);
}

// ---------------- workspace layout ----------------
static const size_t BAR_GRP_OFF  = 0;        // tier A2: per-block flags (256 x 64B); legacy grp
static const size_t BAR_ROOT_OFF = 20480;    // legacy root (tier A/B kernel)
static const size_t CH_OFF  = 24576;                               // 256 KB
static const size_t CL_OFF  = CH_OFF + (size_t)2 * BH * 2;         // 256 KB
static const size_t WX_OFF  = 1u << 20;                            // 8 MB
static const size_t WHH_OFF = WX_OFF  + (size_t)8 * 1024 * 1024;   // 8 MB
static const size_t WHL_OFF = WHH_OFF + (size_t)8 * 1024 * 1024;   // 8 MB
static const size_t XH_OFF  = WHL_OFF + (size_t)8 * 1024 * 1024;   // @25MB
static const size_t X4_OFF  = XH_OFF;                              // tier A2: X4 f16 [32768][4096]
static const size_t TIER_A2_WS = X4_OFF + (size_t)32768 * 4096 * 2;  // ~281 MB
static const size_t TIER_A_WS  = XH_OFF + (size_t)T_STEPS * BH * 2;  // 89 MB
static const size_t TIER_B_WS  = XH_OFF;                             // 25 MB

// ---------------- prep kernels ----------------
__global__ void prep_zero(int* bar) {
    int i = blockIdx.x * 256 + threadIdx.x;
    if (i < 6144) bar[i] = 0;
}

__global__ void prep_w(const float* __restrict__ Wx, const float* __restrict__ Wh,
                       _Float16* __restrict__ wx16,
                       _Float16* __restrict__ whh, _Float16* __restrict__ whl) {
    int i = blockIdx.x * 256 + threadIdx.x;
    if (i < 4 * HD * HD) {
        wx16[i] = (_Float16)Wx[i];
        float w = Wh[i];
        _Float16 h = (_Float16)w;
        whh[i] = h;
        whl[i] = (_Float16)(w - (float)h);
    }
}

__global__ void prep_x(const float* __restrict__ X, _Float16* __restrict__ xh) {
    size_t i = (size_t)blockIdx.x * 256 + threadIdx.x;
    if (i < (size_t)T_STEPS * BH) xh[i] = (_Float16)X[i];
}

// ---------------- X4 GEMM: x4[32768][4096] = X[32768][1024] @ wx16^T ----------------
__global__ __launch_bounds__(256) void x4_gemm(
    const float* __restrict__ X,
    const _Float16* __restrict__ wx16,
    _Float16* __restrict__ x4)
{
    __shared__ _Float16 sA[128][40];
    __shared__ _Float16 sB[128][40];

    const int tid  = threadIdx.x;
    const int wave = tid >> 6;
    const int lane = tid & 63;
    const int m0 = blockIdx.x * 128, n0 = blockIdx.y * 128;
    const int wm = (wave & 1) * 64,  wn = (wave >> 1) * 64;
    const int fm = lane & 15, q = lane >> 4;

    floatx4 acc[4][4];
    #pragma unroll
    for (int i = 0; i < 4; i++)
        #pragma unroll
        for (int j = 0; j < 4; j++)
            acc[i][j] = (floatx4){0.f, 0.f, 0.f, 0.f};

    for (int k0 = 0; k0 < 1024; k0 += 32) {
        {
            const int kq = (tid & 7) * 4;
            const int rb = tid >> 3;
            #pragma unroll
            for (int it = 0; it < 4; it++) {
                int row = rb + it * 32;
                float4v v = *(const float4v*)(X + (size_t)(m0 + row) * 1024 + k0 + kq);
                half4 h; h[0] = (_Float16)v[0]; h[1] = (_Float16)v[1];
                h[2] = (_Float16)v[2]; h[3] = (_Float16)v[3];
                *(half4*)&sA[row][kq] = h;
            }
        }
        {
            const int half = tid & 1;
            const int row  = tid >> 1;
            const _Float16* src = wx16 + (size_t)(n0 + row) * 1024 + k0 + half * 16;
            *(half8*)&sB[row][half * 16]     = *(const half8*)(src);
            *(half8*)&sB[row][half * 16 + 8] = *(const half8*)(src + 8);
        }
        __syncthreads();

        half8 af[4], bf[4];
        #pragma unroll
        for (int i = 0; i < 4; i++) af[i] = *(const half8*)&sA[wm + 16 * i + fm][q * 8];
        #pragma unroll
        for (int j = 0; j < 4; j++) bf[j] = *(const half8*)&sB[wn + 16 * j + fm][q * 8];
        #pragma unroll
        for (int i = 0; i < 4; i++)
            #pragma unroll
            for (int j = 0; j < 4; j++)
                acc[i][j] = __builtin_amdgcn_mfma_f32_16x16x32_f16(af[i], bf[j], acc[i][j], 0, 0, 0);
        __syncthreads();
    }

    #pragma unroll
    for (int i = 0; i < 4; i++)
        #pragma unroll
        for (int j = 0; j < 4; j++)
            #pragma unroll
            for (int r = 0; r < 4; r++) {
                int row = m0 + wm + 16 * i + q * 4 + r;
                int col = n0 + wn + 16 * j + fm;
                x4[(size_t)row * 4096 + col] = (_Float16)acc[i][j][r];
            }
}

// ---------------- legacy grid barrier (tier A/B kernel) ----------------
__device__ __forceinline__ void grid_bar(int* grp, int* root, int slot) {
    __syncthreads();
    if (threadIdx.x == 0) {
        int g = blockIdx.x >> 5;
        int v = __hip_atomic_fetch_add(&grp[slot * 8 + g], 1,
                                       __ATOMIC_ACQ_REL, __HIP_MEMORY_SCOPE_AGENT);
        if (v == 31)
            __hip_atomic_fetch_add(&root[slot], 1,
                                   __ATOMIC_ACQ_REL, __HIP_MEMORY_SCOPE_AGENT);
        while (__hip_atomic_load(&root[slot], __ATOMIC_RELAXED,
                                 __HIP_MEMORY_SCOPE_AGENT) < 8)
            __builtin_amdgcn_s_sleep(2);
        (void)__hip_atomic_load(&root[slot], __ATOMIC_ACQUIRE,
                                __HIP_MEMORY_SCOPE_AGENT);
    }
    __syncthreads();
}

// ---------------- persistent recurrence (tier A2, dataflow-flag sync) ----------------
// 4 independent sub-grids x 64 blocks x 512 threads. Sub-grid owns 16 batches;
// block owns 16 j-cols x 4 gates; all Wh hi/lo in registers; wave = K-chunk
// of 128. NO grid barrier: single-writer per-block flags (sc1 store after
// vmcnt drain); each wave polls only the 8 producer blocks covering its
// K-range. Block-level read-set = all 64 producers -> max slip 1 step ->
// 2-deep c buffers remain race-free (write-phase t needs flags>=t+1, which
// implies every block's step-(t-1) reads completed).
__global__ __launch_bounds__(512, 1) void lstm_persist4(
    const _Float16* __restrict__ x4,   // [T*B][4096]
    const float* __restrict__ h0, const float* __restrict__ c0,
    const float* __restrict__ bias, const int* __restrict__ mask,
    const _Float16* __restrict__ whh, const _Float16* __restrict__ whl,
    _Float16* __restrict__ chg, _Float16* __restrict__ clg,
    int* __restrict__ bar,
    float* __restrict__ out)
{
    __shared__ float s_pre[8][4][16][18];   // 36.9 KB
    __shared__ float s_h[256], s_c[256];

    const int tid  = threadIdx.x;
    const int wave = tid >> 6;     // 0..7 = K-chunk
    const int lane = tid & 63;
    const int sg   = blockIdx.x >> 6;   // 0..3
    const int lb   = blockIdx.x & 63;   // 0..63
    const int b0   = sg * BSG;
    const int j0   = lb * JBLK;

    // per-block flag, 64B padded, single writer; wave polls its 8 producers
    int*       myflag = bar + (((sg << 6) | lb) << 4);
    const int* pflag  = bar + (((sg << 6) | (wave << 3) | (lane & 7)) << 4);

    const int nn    = lane & 15;          // j-local (B-frag row)
    const int q     = lane >> 4;
    const int kbase = wave * 128 + q * 8;
    const int arow  = lane & 15;          // batch-local (A-frag row)

    // ---- all weights (hi + lo) into registers: 4 gates x 4 k-iters ----
    half8 wh_[4][4], wl_[4][4];
    #pragma unroll
    for (int g = 0; g < 4; g++) {
        const size_t wr = (size_t)(g * HD + j0 + nn) * HD + kbase;
        #pragma unroll
        for (int k = 0; k < 4; k++) {
            wh_[g][k] = *(const half8*)(whh + wr + k * 32);
            wl_[g][k] = *(const half8*)(whl + wr + k * 32);
        }
    }

    // ---- init gate state, publish c0, prefetch t=0 gate inputs ----
    float biasr[4] = {0.f, 0.f, 0.f, 0.f};
    float xg[4]    = {0.f, 0.f, 0.f, 0.f};
    int   mv       = 0;
    if (tid < 256) {
        int bl = tid >> 4, n = tid & 15;
        int b = b0 + bl, j = j0 + n;
        float cv = c0[b * HD + j];
        s_c[tid] = cv;
        s_h[tid] = h0[b * HD + j];
        #pragma unroll
        for (int g = 0; g < 4; g++) biasr[g] = bias[g * HD + j];

        _Float16 chi = (_Float16)cv;
        _Float16 clo = (_Float16)(cv - (float)chi);
        unsigned pk = (unsigned)__builtin_bit_cast(unsigned short, chi)
                    | ((unsigned)__builtin_bit_cast(unsigned short, clo) << 16);
        unsigned p1 = __shfl_down(pk, 1);
        unsigned p2 = __shfl_down(pk, 2);
        unsigned p3 = __shfl_down(pk, 3);
        if ((n & 3) == 0) {
            st_sc1_b64(chg + b * HD + j0 + (n & ~3), pack_lo16(pk, p1, p2, p3));
            st_sc1_b64(clg + b * HD + j0 + (n & ~3), pack_hi16(pk, p1, p2, p3));
        }
        #pragma unroll
        for (int g = 0; g < 4; g++)
            xg[g] = (float)x4[(size_t)b * 4096 + g * HD + j];
        mv = mask[b];
        asm volatile("s_waitcnt vmcnt(0)" ::: "memory");
    }
    __syncthreads();
    if (tid == 0)
        __hip_atomic_store(myflag, 1, __ATOMIC_RELAXED, __HIP_MEMORY_SCOPE_AGENT);

    for (int t = 0; t < T_STEPS; t++) {
        const int cur = t & 1;

        // ---- wait for this wave's 8 producers to publish buffer `cur` ----
        const int need = t + 1;
        int fv = __hip_atomic_load(pflag, __ATOMIC_RELAXED, __HIP_MEMORY_SCOPE_AGENT);
        while (!__all(fv >= need)) {
            __builtin_amdgcn_s_sleep(1);
            fv = __hip_atomic_load(pflag, __ATOMIC_RELAXED, __HIP_MEMORY_SCOPE_AGENT);
        }

        const _Float16* chp = chg + (size_t)cur * BH + (size_t)(b0 + arow) * HD + kbase;
        const _Float16* clp = clg + (size_t)cur * BH + (size_t)(b0 + arow) * HD + kbase;

        // 8x b128 sc0|sc1 loads (bypass L1+L2, read L3) + single wait
        half8 a0, a1, a2, a3, l0, l1, l2, l3;
        asm volatile(
            "global_load_dwordx4 %0, %8, off sc0 sc1\n\t"
            "global_load_dwordx4 %1, %8, off offset:64 sc0 sc1\n\t"
            "global_load_dwordx4 %2, %8, off offset:128 sc0 sc1\n\t"
            "global_load_dwordx4 %3, %8, off offset:192 sc0 sc1\n\t"
            "global_load_dwordx4 %4, %9, off sc0 sc1\n\t"
            "global_load_dwordx4 %5, %9, off offset:64 sc0 sc1\n\t"
            "global_load_dwordx4 %6, %9, off offset:128 sc0 sc1\n\t"
            "global_load_dwordx4 %7, %9, off offset:192 sc0 sc1\n\t"
            "s_waitcnt vmcnt(0)"
            : "=&v"(a0), "=&v"(a1), "=&v"(a2), "=&v"(a3),
              "=&v"(l0), "=&v"(l1), "=&v"(l2), "=&v"(l3)
            : "v"(chp), "v"(clp)
            : "memory");

        floatx4 acc[4];
        #pragma unroll
        for (int g = 0; g < 4; g++) acc[g] = (floatx4){0.f, 0.f, 0.f, 0.f};
        #pragma unroll
        for (int g = 0; g < 4; g++) {
            floatx4 t0 = acc[g];
            t0 = __builtin_amdgcn_mfma_f32_16x16x32_f16(a0, wh_[g][0], t0, 0, 0, 0);
            t0 = __builtin_amdgcn_mfma_f32_16x16x32_f16(l0, wh_[g][0], t0, 0, 0, 0);
            t0 = __builtin_amdgcn_mfma_f32_16x16x32_f16(a0, wl_[g][0], t0, 0, 0, 0);
            t0 = __builtin_amdgcn_mfma_f32_16x16x32_f16(a1, wh_[g][1], t0, 0, 0, 0);
            t0 = __builtin_amdgcn_mfma_f32_16x16x32_f16(l1, wh_[g][1], t0, 0, 0, 0);
            t0 = __builtin_amdgcn_mfma_f32_16x16x32_f16(a1, wl_[g][1], t0, 0, 0, 0);
            t0 = __builtin_amdgcn_mfma_f32_16x16x32_f16(a2, wh_[g][2], t0, 0, 0, 0);
            t0 = __builtin_amdgcn_mfma_f32_16x16x32_f16(l2, wh_[g][2], t0, 0, 0, 0);
            t0 = __builtin_amdgcn_mfma_f32_16x16x32_f16(a2, wl_[g][2], t0, 0, 0, 0);
            t0 = __builtin_amdgcn_mfma_f32_16x16x32_f16(a3, wh_[g][3], t0, 0, 0, 0);
            t0 = __builtin_amdgcn_mfma_f32_16x16x32_f16(l3, wh_[g][3], t0, 0, 0, 0);
            t0 = __builtin_amdgcn_mfma_f32_16x16x32_f16(a3, wl_[g][3], t0, 0, 0, 0);
            acc[g] = t0;
        }

        #pragma unroll
        for (int g = 0; g < 4; g++) {
            s_pre[wave][g][q * 4 + 0][nn] = acc[g][0];
            s_pre[wave][g][q * 4 + 1][nn] = acc[g][1];
            s_pre[wave][g][q * 4 + 2][nn] = acc[g][2];
            s_pre[wave][g][q * 4 + 3][nn] = acc[g][3];
        }
        __syncthreads();

        float h_out = 0.f, c_out = 0.f;
        if (tid < 256) {
            int bl = tid >> 4, n = tid & 15;
            int b = b0 + bl, j = j0 + n;

            float pg[4];
            #pragma unroll
            for (int g = 0; g < 4; g++) {
                float s = xg[g] + biasr[g];
                #pragma unroll
                for (int kh = 0; kh < 8; kh++)
                    s += s_pre[kh][g][bl][n];
                pg[g] = s;
            }

            float c_old = s_c[tid];
            float i_g = sigmoidf_(pg[0]);
            float f_g = sigmoidf_(pg[1]);
            float o_g = sigmoidf_(pg[2]);
            float g_g = tanhf(pg[3]);
            float c_new = f_g * c_old + i_g * g_g;
            float h_new = o_g * tanhf(c_new);

            h_out = mv ? h_new : s_h[tid];
            c_out = mv ? c_new : c_old;
            s_h[tid] = h_out;
            s_c[tid] = c_out;

            _Float16 chi = (_Float16)c_out;
            _Float16 clo = (_Float16)(c_out - (float)chi);
            unsigned pk = (unsigned)__builtin_bit_cast(unsigned short, chi)
                        | ((unsigned)__builtin_bit_cast(unsigned short, clo) << 16);
            unsigned p1 = __shfl_down(pk, 1);
            unsigned p2 = __shfl_down(pk, 2);
            unsigned p3 = __shfl_down(pk, 3);
            if ((n & 3) == 0) {
                int nxt = cur ^ 1;
                st_sc1_b64(chg + (size_t)nxt * BH + (size_t)b * HD + j0 + (n & ~3),
                           pack_lo16(pk, p1, p2, p3));
                st_sc1_b64(clg + (size_t)nxt * BH + (size_t)b * HD + j0 + (n & ~3),
                           pack_hi16(pk, p1, p2, p3));
            }
            // drain c stores (everything else outstanding is long done)
            asm volatile("s_waitcnt vmcnt(0)" ::: "memory");
        }
        __syncthreads();
        if (tid == 0)
            __hip_atomic_store(myflag, t + 2, __ATOMIC_RELAXED, __HIP_MEMORY_SCOPE_AGENT);

        if (tid < 256) {
            int bl = tid >> 4, n = tid & 15;
            int b = b0 + bl, j = j0 + n;
            // out store AFTER flag publish: its HBM ack never gates the flag
            out[(size_t)t * BH + (size_t)b * HD + j] = h_out;
            if (t == T_STEPS - 1) {
                size_t tail = (size_t)T_STEPS * BH;
                out[tail + (size_t)b * HD + j]      = h_out;
                out[tail + BH + (size_t)b * HD + j] = c_out;
            }
            // prefetch NEXT step's gate inputs + mask: overlaps next poll,
            // c-load and MFMA phases
            int tn = (t + 1 < T_STEPS) ? t + 1 : t;
            #pragma unroll
            for (int g = 0; g < 4; g++)
                xg[g] = (float)x4[((size_t)tn * BATCH + b) * 4096 + g * HD + j];
            mv = mask[tn * BATCH + b];
        }
    }
}

// ---------------- tier A/B persistent kernel (round-3, proven) ----------------
template<bool XF16>
__global__ __launch_bounds__(1024, 4) void lstm_persist(
    const float* __restrict__ X, const _Float16* __restrict__ xh,
    const float* __restrict__ h0, const float* __restrict__ c0,
    const float* __restrict__ bias, const int* __restrict__ mask,
    const _Float16* __restrict__ wx16, const _Float16* __restrict__ whh,
    const _Float16* __restrict__ whl,
    _Float16* __restrict__ chg, _Float16* __restrict__ clg,
    int* __restrict__ barg, int* __restrict__ barr,
    float* __restrict__ out)
{
    __shared__ _Float16 s_wh[16 * 1032];
    __shared__ float    s_pre[16][16][17];
    __shared__ float    s_h[256], s_c[256];

    const int tid  = threadIdx.x;
    const int wave = tid >> 6;
    const int lane = tid & 63;
    const int j0   = blockIdx.x * 4;

    for (int idx = tid; idx < 2048; idx += 1024) {
        int n  = idx >> 7;
        int kk = (idx & 127) << 3;
        int r  = (n >> 2) * HD + j0 + (n & 3);
        *(half8*)&s_wh[n * 1032 + kk] = *(const half8*)(whh + (size_t)r * HD + kk);
    }

    float biasr[4] = {0.f, 0.f, 0.f, 0.f};
    if (tid < 256) {
        int b = tid >> 2, jj = tid & 3, j = j0 + jj;
        float cv = c0[b * HD + j];
        s_c[tid] = cv;
        s_h[tid] = h0[b * HD + j];
        _Float16 hi = (_Float16)cv;
        chg[b * HD + j] = hi;
        clg[b * HD + j] = (_Float16)(cv - (float)hi);
        #pragma unroll
        for (int g = 0; g < 4; g++) biasr[g] = bias[g * HD + j];
    }
    grid_bar(barg, barr, 0);

    const int mt    = wave & 3;
    const int kh    = wave >> 2;
    const int arow  = mt * 16 + (lane & 15);
    const int nn    = lane & 15;
    const int q     = lane >> 4;
    const int kbase = kh * 256 + q * 8;
    const int wrow  = (nn >> 2) * HD + j0 + (nn & 3);

    const _Float16* wxp = wx16 + (size_t)wrow * HD + kbase;
    const _Float16* wlp = whl  + (size_t)wrow * HD + kbase;
    const _Float16* whp = (const _Float16*)&s_wh[nn * 1032 + kbase];

    for (int t = 0; t < T_STEPS; t++) {
        const int cur = t & 1;
        const _Float16* chp = chg + (size_t)cur * BH + (size_t)arow * HD + kbase;
        const _Float16* clp = clg + (size_t)cur * BH + (size_t)arow * HD + kbase;

        floatx4 acc = {0.f, 0.f, 0.f, 0.f};

        if (XF16) {
            const _Float16* xp = xh + (size_t)t * BH + (size_t)arow * HD + kbase;
            #pragma unroll 4
            for (int k = 0; k < 256; k += 32) {
                half8 av = *(const half8*)(xp + k);
                half8 bv = *(const half8*)(wxp + k);
                acc = __builtin_amdgcn_mfma_f32_16x16x32_f16(av, bv, acc, 0, 0, 0);
            }
        } else {
            const float* xp = X + (size_t)t * BH + (size_t)arow * HD + kbase;
            #pragma unroll 4
            for (int k = 0; k < 256; k += 32) {
                float4v x0 = *(const float4v*)(xp + k);
                float4v x1 = *(const float4v*)(xp + k + 4);
                half8 av = cvt_h8(x0, x1);
                half8 bv = *(const half8*)(wxp + k);
                acc = __builtin_amdgcn_mfma_f32_16x16x32_f16(av, bv, acc, 0, 0, 0);
            }
        }

        #pragma unroll 4
        for (int k = 0; k < 256; k += 32) {
            half8 ah = *(const half8*)(chp + k);
            half8 al = *(const half8*)(clp + k);
            half8 bh = *(const half8*)(whp + k);
            half8 bl = *(const half8*)(wlp + k);
            acc = __builtin_amdgcn_mfma_f32_16x16x32_f16(ah, bh, acc, 0, 0, 0);
            acc = __builtin_amdgcn_mfma_f32_16x16x32_f16(al, bh, acc, 0, 0, 0);
            acc = __builtin_amdgcn_mfma_f32_16x16x32_f16(ah, bl, acc, 0, 0, 0);
        }

        s_pre[wave][q * 4 + 0][nn] = acc[0];
        s_pre[wave][q * 4 + 1][nn] = acc[1];
        s_pre[wave][q * 4 + 2][nn] = acc[2];
        s_pre[wave][q * 4 + 3][nn] = acc[3];
        __syncthreads();

        if (tid < 256) {
            int b = tid >> 2, jj = tid & 3, j = j0 + jj;
            int m = b & 15, mtt = b >> 4;

            float pg[4];
            #pragma unroll
            for (int g = 0; g < 4; g++) {
                float s = 0.f;
                #pragma unroll
                for (int kk = 0; kk < 4; kk++)
                    s += s_pre[kk * 4 + mtt][m][g * 4 + jj];
                pg[g] = s + biasr[g];
            }

            float c_old = s_c[tid];
            float i_g = sigmoidf_(pg[0]);
            float f_g = sigmoidf_(pg[1]);
            float o_g = sigmoidf_(pg[2]);
            float g_g = tanhf(pg[3]);
            float c_new = f_g * c_old + i_g * g_g;
            float h_new = o_g * tanhf(c_new);

            int mv = mask[t * BATCH + b];
            float h_out = mv ? h_new : s_h[tid];
            float c_out = mv ? c_new : c_old;
            s_h[tid] = h_out;
            s_c[tid] = c_out;

            int nxt = cur ^ 1;
            _Float16 hi = (_Float16)c_out;
            chg[(size_t)nxt * BH + b * HD + j] = hi;
            clg[(size_t)nxt * BH + b * HD + j] = (_Float16)(c_out - (float)hi);
            out[(size_t)t * BH + b * HD + j] = h_out;

            if (t == T_STEPS - 1) {
                size_t tail = (size_t)T_STEPS * BH;
                out[tail + b * HD + j]      = h_out;
                out[tail + BH + b * HD + j] = c_out;
            }
        }
        grid_bar(barg, barr, t + 1);
    }
}

// ---------------- tiny-ws fallback: per-step kernel ----------------
__global__ void init_c_fb(const float* __restrict__ c0, float* __restrict__ cf,
                          _Float16* __restrict__ ch, _Float16* __restrict__ cl) {
    int i = blockIdx.x * 256 + threadIdx.x;
    if (i < BH) {
        float v = c0[i];
        cf[i] = v;
        _Float16 h = (_Float16)v;
        ch[i] = h;
        cl[i] = (_Float16)(v - (float)h);
    }
}

__global__ __launch_bounds__(1024) void lstm_step_fb(
    const float* __restrict__ X, const float* __restrict__ h0,
    const float* __restrict__ Wx, const float* __restrict__ Wh,
    const float* __restrict__ bias, const int* __restrict__ mask,
    float* __restrict__ cf, _Float16* __restrict__ chbuf, _Float16* __restrict__ clbuf,
    float* __restrict__ out, int t)
{
    __shared__ float lds_pre[4][64][16];
    const int tid = threadIdx.x, wave = tid >> 6, lane = tid & 63;
    const int g = wave & 3, mt = wave >> 2, j0 = blockIdx.x * 16;
    const int cur = t & 1;
    const float* cf_prev = cf + (size_t)cur * BH;
    const _Float16* ch_prev = chbuf + (size_t)cur * BH;
    const _Float16* cl_prev = clbuf + (size_t)cur * BH;
    float* cf_next = cf + (size_t)(cur ^ 1) * BH;
    _Float16* ch_next = chbuf + (size_t)(cur ^ 1) * BH;
    _Float16* cl_next = clbuf + (size_t)(cur ^ 1) * BH;
    const int arow = mt * 16 + (lane & 15);
    const int brow = g * HD + j0 + (lane & 15);
    const int koff = (lane >> 4) * 8;
    floatx4 acc = {0.f, 0.f, 0.f, 0.f};
    {
        const float* xp = X + (size_t)t * BH + (size_t)arow * HD + koff;
        const float* wp = Wx + (size_t)brow * HD + koff;
        #pragma unroll 4
        for (int k = 0; k < HD; k += 32) {
            float4v x0 = *(const float4v*)(xp + k);
            float4v x1 = *(const float4v*)(xp + k + 4);
            float4v w0 = *(const float4v*)(wp + k);
            float4v w1 = *(const float4v*)(wp + k + 4);
            acc = __builtin_amdgcn_mfma_f32_16x16x32_f16(cvt_h8(x0, x1), cvt_h8(w0, w1), acc, 0, 0, 0);
        }
    }
    {
        const _Float16* chp = ch_prev + (size_t)arow * HD + koff;
        const _Float16* clp = cl_prev + (size_t)arow * HD + koff;
        const float* whp = Wh + (size_t)brow * HD + koff;
        #pragma unroll 4
        for (int k = 0; k < HD; k += 32) {
            half8 ah = *(const half8*)(chp + k);
            half8 al = *(const half8*)(clp + k);
            float4v w0 = *(const float4v*)(whp + k);
            float4v w1 = *(const float4v*)(whp + k + 4);
            half8 bh = cvt_h8(w0, w1);
            float4v r0, r1;
            r0[0] = w0[0] - (float)bh[0]; r0[1] = w0[1] - (float)bh[1];
            r0[2] = w0[2] - (float)bh[2]; r0[3] = w0[3] - (float)bh[3];
            r1[0] = w1[0] - (float)bh[4]; r1[1] = w1[1] - (float)bh[5];
            r1[2] = w1[2] - (float)bh[6]; r1[3] = w1[3] - (float)bh[7];
            half8 bl = cvt_h8(r0, r1);
            acc = __builtin_amdgcn_mfma_f32_16x16x32_f16(ah, bh, acc, 0, 0, 0);
            acc = __builtin_amdgcn_mfma_f32_16x16x32_f16(al, bh, acc, 0, 0, 0);
            acc = __builtin_amdgcn_mfma_f32_16x16x32_f16(ah, bl, acc, 0, 0, 0);
        }
    }
    {
        const int qq = lane >> 4, col = lane & 15;
        lds_pre[g][mt * 16 + qq * 4 + 0][col] = acc[0];
        lds_pre[g][mt * 16 + qq * 4 + 1][col] = acc[1];
        lds_pre[g][mt * 16 + qq * 4 + 2][col] = acc[2];
        lds_pre[g][mt * 16 + qq * 4 + 3][col] = acc[3];
    }
    __syncthreads();
    {
        const int bl2 = tid >> 4, n = tid & 15, j = j0 + n;
        float pg[4];
        #pragma unroll
        for (int gg = 0; gg < 4; gg++) pg[gg] = lds_pre[gg][bl2][n] + bias[gg * HD + j];
        float c_old = cf_prev[bl2 * HD + j];
        float i_g = sigmoidf_(pg[0]), f_g = sigmoidf_(pg[1]);
        float o_g = sigmoidf_(pg[2]), g_g = tanhf(pg[3]);
        float c_new = f_g * c_old + i_g * g_g;
        float h_new = o_g * tanhf(c_new);
        int mv = mask[t * BATCH + bl2];
        float h_prev = (t == 0) ? h0[bl2 * HD + j] : out[(size_t)(t - 1) * BH + bl2 * HD + j];
        float h_out = mv ? h_new : h_prev;
        float c_out = mv ? c_new : c_old;
        cf_next[bl2 * HD + j] = c_out;
        _Float16 hh = (_Float16)c_out;
        ch_next[bl2 * HD + j] = hh;
        cl_next[bl2 * HD + j] = (_Float16)(c_out - (float)hh);
        out[(size_t)t * BH + bl2 * HD + j] = h_out;
        if (t == T_STEPS - 1) {
            size_t tail = (size_t)T_STEPS * BH;
            out[tail + bl2 * HD + j] = h_out;
            out[tail + BH + bl2 * HD + j] = c_out;
        }
    }
}

// ---------------- launch ----------------
extern "C" void kernel_launch(void* const* d_in, const int* in_sizes, int n_in,
                              void* d_out, int out_size, void* d_ws, size_t ws_size,
                              hipStream_t stream) {
    const float* X    = (const float*)d_in[0];
    const float* h0   = (const float*)d_in[1];
    const float* c0   = (const float*)d_in[2];
    const int*   mask = (const int*)  d_in[3];
    const float* Wx   = (const float*)d_in[4];
    const float* Wh   = (const float*)d_in[5];
    const float* bias = (const float*)d_in[6];
    float* out = (float*)d_out;
    char* ws = (char*)d_ws;

    if (ws_size >= TIER_B_WS) {
        int*      barg = (int*)(ws + BAR_GRP_OFF);
        int*      barr = (int*)(ws + BAR_ROOT_OFF);
        _Float16* chg  = (_Float16*)(ws + CH_OFF);
        _Float16* clg  = (_Float16*)(ws + CL_OFF);
        _Float16* wx16 = (_Float16*)(ws + WX_OFF);
        _Float16* whh  = (_Float16*)(ws + WHH_OFF);
        _Float16* whl  = (_Float16*)(ws + WHL_OFF);

        prep_zero<<<dim3(24), dim3(256), 0, stream>>>(barg);
        prep_w<<<dim3(16384), dim3(256), 0, stream>>>(Wx, Wh, wx16, whh, whl);

        if (ws_size >= TIER_A2_WS) {
            _Float16* x4 = (_Float16*)(ws + X4_OFF);
            x4_gemm<<<dim3(256, 32), dim3(256), 0, stream>>>(X, wx16, x4);
            void* args[] = {
                (void*)&x4, (void*)&h0, (void*)&c0, (void*)&bias, (void*)&mask,
                (void*)&whh, (void*)&whl, (void*)&chg, (void*)&clg,
                (void*)&barg, (void*)&out
            };
            hipLaunchCooperativeKernel((const void*)&lstm_persist4,
                                       dim3(NBLK), dim3(512), args, 0, stream);
        } else {
            _Float16* xh = (_Float16*)(ws + XH_OFF);
            const bool tierA = ws_size >= TIER_A_WS;
            if (tierA)
                prep_x<<<dim3(131072), dim3(256), 0, stream>>>(X, xh);
            void* args[] = {
                (void*)&X, (void*)&xh, (void*)&h0, (void*)&c0, (void*)&bias,
                (void*)&mask, (void*)&wx16, (void*)&whh, (void*)&whl,
                (void*)&chg, (void*)&clg, (void*)&barg, (void*)&barr, (void*)&out
            };
            if (tierA)
                hipLaunchCooperativeKernel((const void*)&lstm_persist<true>,
                                           dim3(NBLK), dim3(1024), args, 0, stream);
            else
                hipLaunchCooperativeKernel((const void*)&lstm_persist<false>,
                                           dim3(NBLK), dim3(1024), args, 0, stream);
        }
    } else {
        float*    cf = (float*)ws;
        _Float16* ch = (_Float16*)(ws + 524288);
        _Float16* cl = (_Float16*)(ws + 786432);
        init_c_fb<<<dim3((BH + 255) / 256), dim3(256), 0, stream>>>(c0, cf, ch, cl);
        for (int t = 0; t < T_STEPS; t++)
            lstm_step_fb<<<dim3(64), dim3(1024), 0, stream>>>(
                X, h0, Wx, Wh, bias, mask, cf, ch, cl, out, t);
    }
}